// Round 9
// baseline (346.827 us; speedup 1.0000x reference)
//
#include <hip/hip_runtime.h>
#include <cstdint>
#include <cstddef>

#define NEG_SLOPE 0.2f

typedef __bf16 bf16x8 __attribute__((ext_vector_type(8)));
typedef __bf16 bf16x4 __attribute__((ext_vector_type(4)));
typedef float f32x4 __attribute__((ext_vector_type(4)));

// ---------- merged independent prep: prep_v1 | prep_v2 | W1 transpose | deg ----------
__global__ __launch_bounds__(256) void prep_all_kernel(
    const float* __restrict__ W1, const float* __restrict__ as1, const float* __restrict__ ad1,
    const float* __restrict__ W2, const float* __restrict__ as2, const float* __restrict__ ad2,
    const int* __restrict__ ei, int E,
    float* __restrict__ Vs, float* __restrict__ Vd,
    float* __restrict__ vs2, float* __restrict__ vd2,
    __bf16* __restrict__ W1T, int* __restrict__ deg) {
  int bid = blockIdx.x, tid = threadIdx.x;
  if (bid == 0) {
    int k = tid >> 2, h = tid & 3;
    const float* w = W1 + k * 512 + h * 128;
    const float* a1 = as1 + h * 128;
    const float* a2 = ad1 + h * 128;
    float s = 0.f, d = 0.f;
    for (int c = 0; c < 128; ++c) { float wv = w[c]; s += wv * a1[c]; d += wv * a2[c]; }
    Vs[k * 4 + h] = s; Vd[k * 4 + h] = d;
  } else if (bid <= 2) {
    int k = (bid - 1) * 256 + tid;
    if (k < 512) {
      const float* w = W2 + k * 256;
      float s = 0.f, d = 0.f;
      for (int c = 0; c < 256; ++c) { float wv = w[c]; s += wv * as2[c]; d += wv * ad2[c]; }
      vs2[k] = s; vd2[k] = d;
    }
  } else if (bid <= 130) {
    int idx = (bid - 3) * 256 + tid;   // < 32768
    int n = idx >> 6, k = idx & 63;    // W1T[n*64+k] = W1[k*512+n]
    W1T[idx] = (__bf16)W1[(size_t)k * 512 + n];
  } else {
    int t = (bid - 131) * 256 + tid;
    int base = t * 4;
    if (base >= E) return;
    if (base + 4 <= E) {
      int4 d4 = *(const int4*)(ei + E + base);
      atomicAdd(&deg[d4.x], 1);
      atomicAdd(&deg[d4.y], 1);
      atomicAdd(&deg[d4.z], 1);
      atomicAdd(&deg[d4.w], 1);
    } else {
      for (int e = base; e < E; ++e) atomicAdd(&deg[ei[E + e]], 1);
    }
  }
}

// ---------- fused emb -> bf16 + alpha1 ----------
__global__ void emb_prep_kernel(const float* __restrict__ emb, const float* __restrict__ Vs,
                                const float* __restrict__ Vd, __bf16* __restrict__ embb,
                                float* __restrict__ as_, float* __restrict__ ad_, int n) {
  __shared__ float sVs[256];
  __shared__ float sVd[256];
  for (int i = threadIdx.x; i < 256; i += blockDim.x) { sVs[i] = Vs[i]; sVd[i] = Vd[i]; }
  __syncthreads();
  int node = blockIdx.x * blockDim.x + threadIdx.x;
  if (node >= n) return;
  const float* xr = emb + (size_t)node * 64;
  __bf16* br = embb + (size_t)node * 64;
  float accs[4] = {}, accd[4] = {};
  for (int k = 0; k < 64; k += 4) {
    float4 xv = *(const float4*)(xr + k);
    bf16x4 o;
    o[0] = (__bf16)xv.x; o[1] = (__bf16)xv.y; o[2] = (__bf16)xv.z; o[3] = (__bf16)xv.w;
    *(bf16x4*)(br + k) = o;
#pragma unroll
    for (int h = 0; h < 4; ++h) {
      accs[h] += xv.x * sVs[(k + 0) * 4 + h] + xv.y * sVs[(k + 1) * 4 + h] +
                 xv.z * sVs[(k + 2) * 4 + h] + xv.w * sVs[(k + 3) * 4 + h];
      accd[h] += xv.x * sVd[(k + 0) * 4 + h] + xv.y * sVd[(k + 1) * 4 + h] +
                 xv.z * sVd[(k + 2) * 4 + h] + xv.w * sVd[(k + 3) * 4 + h];
    }
  }
#pragma unroll
  for (int h = 0; h < 4; ++h) {
    as_[(size_t)node * 4 + h] = accs[h];
    ad_[(size_t)node * 4 + h] = accd[h];
  }
}

// ---------- CSR scan ----------
__global__ void scan_reduce_kernel(const int* __restrict__ deg, int* __restrict__ partial, int n) {
  __shared__ int ws[4];
  int i = blockIdx.x * 256 + threadIdx.x;
  int v = (i < n) ? deg[i] + 1 : 0;
  int lane = threadIdx.x & 63, w = threadIdx.x >> 6;
#pragma unroll
  for (int s = 32; s; s >>= 1) v += __shfl_down(v, s, 64);
  if (lane == 0) ws[w] = v;
  __syncthreads();
  if (threadIdx.x == 0) partial[blockIdx.x] = ws[0] + ws[1] + ws[2] + ws[3];
}

__global__ void scan_final_kernel(const int* __restrict__ deg, const int* __restrict__ partial,
                                  int* __restrict__ off, int n) {
  __shared__ int ws[4];
  __shared__ int bsum[4];
  __shared__ int sbase;
  int b = blockIdx.x, t = threadIdx.x;
  int lane = t & 63, w = t >> 6;
  int ps = (t < b) ? partial[t] : 0;    // b <= 255 assumed
#pragma unroll
  for (int s = 32; s; s >>= 1) ps += __shfl_down(ps, s, 64);
  if (lane == 0) bsum[w] = ps;
  __syncthreads();
  if (t == 0) sbase = bsum[0] + bsum[1] + bsum[2] + bsum[3];
  int i = b * 256 + t;
  int v = (i < n) ? deg[i] + 1 : 0;
  int x = v;
#pragma unroll
  for (int s = 1; s < 64; s <<= 1) {
    int tt = __shfl_up(x, s, 64);
    if (lane >= s) x += tt;
  }
  if (lane == 63) ws[w] = x;
  __syncthreads();
  int wo = 0;
  for (int k = 0; k < w; ++k) wo += ws[k];
  int base = sbase;
  if (i < n) off[i] = base + wo + x - v;
  if (i == n - 1) off[n] = base + wo + x;
}

// ---------- scatter real edges + self-loop tail slot ----------
__global__ void scatter_kernel(const int* __restrict__ ei, int E, const int* __restrict__ off,
                               int* __restrict__ cursor, int* __restrict__ csr_src, int n,
                               int scatterBlocks) {
  if ((int)blockIdx.x < scatterBlocks) {
    int e = blockIdx.x * 256 + threadIdx.x;
    if (e >= E) return;
    int s = ei[e], d = ei[E + e];
    int p = atomicAdd(&cursor[d], 1);
    csr_src[off[d] + p] = s;
  } else {
    int d = (blockIdx.x - scatterBlocks) * 256 + threadIdx.x;
    if (d < n) csr_src[off[d + 1] - 1] = d;
  }
}

// ---------- layer-1 aggregation in EMBEDDING space, 8 edges in flight ----------
// wave = 8 groups of 8 lanes; group g processes edge beg+it*8+g; lane p covers chans p*8..p*8+7
__global__ __launch_bounds__(128) void agg_emb_kernel(
    const int* __restrict__ off, const int* __restrict__ csr_src,
    const __bf16* __restrict__ embb, const float* __restrict__ as_,
    const float* __restrict__ ad_, __bf16* __restrict__ aggE) {
  int d = blockIdx.x * 2 + (threadIdx.x >> 6);
  int lane = threadIdx.x & 63;
  int g = lane >> 3, p = lane & 7;
  float4 adv = *(const float4*)(ad_ + (size_t)d * 4);
  float acc[4][8] = {};   // [head][chan]
  float wsum[4] = {};
  int beg = off[d], end = off[d + 1];
  for (int i0 = beg; i0 < end; i0 += 8) {
    int i = i0 + g;
    float vm = (i < end) ? 1.f : 0.f;
    int idx = (i < end) ? i : (end - 1);
    int s = csr_src[idx];
    float4 asv = *(const float4*)(as_ + (size_t)s * 4);
    float l0 = asv.x + adv.x; l0 = l0 >= 0.f ? l0 : NEG_SLOPE * l0;
    float l1 = asv.y + adv.y; l1 = l1 >= 0.f ? l1 : NEG_SLOPE * l1;
    float l2 = asv.z + adv.z; l2 = l2 >= 0.f ? l2 : NEG_SLOPE * l2;
    float l3 = asv.w + adv.w; l3 = l3 >= 0.f ? l3 : NEG_SLOPE * l3;
    float w0 = __expf(l0) * vm, w1 = __expf(l1) * vm;
    float w2 = __expf(l2) * vm, w3 = __expf(l3) * vm;
    bf16x8 v = *(const bf16x8*)(embb + (size_t)s * 64 + p * 8);
    float f[8];
#pragma unroll
    for (int c = 0; c < 8; ++c) f[c] = (float)v[c];
#pragma unroll
    for (int c = 0; c < 8; ++c) {
      acc[0][c] += w0 * f[c];
      acc[1][c] += w1 * f[c];
      acc[2][c] += w2 * f[c];
      acc[3][c] += w3 * f[c];
    }
    wsum[0] += w0; wsum[1] += w1; wsum[2] += w2; wsum[3] += w3;
  }
  // reduce across the 8 groups (lane bits 3,4,5)
#pragma unroll
  for (int h = 0; h < 4; ++h) {
#pragma unroll
    for (int c = 0; c < 8; ++c) {
      acc[h][c] += __shfl_xor(acc[h][c], 8, 64);
      acc[h][c] += __shfl_xor(acc[h][c], 16, 64);
      acc[h][c] += __shfl_xor(acc[h][c], 32, 64);
    }
    wsum[h] += __shfl_xor(wsum[h], 8, 64);
    wsum[h] += __shfl_xor(wsum[h], 16, 64);
    wsum[h] += __shfl_xor(wsum[h], 32, 64);
  }
  if (g == 0) {
#pragma unroll
    for (int h = 0; h < 4; ++h) {
      float inv = 1.0f / wsum[h];
      bf16x8 o;
#pragma unroll
      for (int c = 0; c < 8; ++c) o[c] = (__bf16)(acc[h][c] * inv);
      *(bf16x8*)(aggE + (size_t)d * 256 + h * 64 + p * 8) = o;
    }
  }
}

// ---------- reconstruct x1 (per-head MFMA GEMM + bias + ELU) with fused alpha2 partials ----------
__global__ __launch_bounds__(256) void gemm1p_kernel(const __bf16* __restrict__ aggE,
                                                     const __bf16* __restrict__ W1T,
                                                     const float* __restrict__ b1,
                                                     const float* __restrict__ vs2,
                                                     const float* __restrict__ vd2,
                                                     __bf16* __restrict__ x1,
                                                     float* __restrict__ as2p,
                                                     float* __restrict__ ad2p, int M) {
  __shared__ __bf16 Asl[128 * 72];
  __shared__ __bf16 Bsl[128 * 72];
  int tid = threadIdx.x;
  int h = blockIdx.z;
  int m0 = blockIdx.x * 128;
  int wave = tid >> 6, lane = tid & 63;
  int wm = (wave >> 1) * 64, wn = (wave & 1) * 64;
  int l15 = lane & 15, kg = lane >> 4;
#pragma unroll
  for (int i = 0; i < 4; ++i) {
    int c = tid + i * 256;
    int row = c >> 3, off = (c & 7) * 8;
    bf16x8 va = {};
    int gr = m0 + row;
    if (gr < M) va = *(const bf16x8*)(aggE + (size_t)gr * 256 + h * 64 + off);
    *(bf16x8*)(&Asl[row * 72 + off]) = va;
    bf16x8 vb = *(const bf16x8*)(W1T + ((size_t)h * 128 + row) * 64 + off);
    *(bf16x8*)(&Bsl[row * 72 + off]) = vb;
  }
  __syncthreads();
  f32x4 acc[4][4] = {};
#pragma unroll
  for (int ks = 0; ks < 2; ++ks) {
    bf16x8 af[4], bfr[4];
#pragma unroll
    for (int f = 0; f < 4; ++f) {
      af[f]  = *(const bf16x8*)(&Asl[(wm + f * 16 + l15) * 72 + kg * 8 + ks * 32]);
      bfr[f] = *(const bf16x8*)(&Bsl[(wn + f * 16 + l15) * 72 + kg * 8 + ks * 32]);
    }
#pragma unroll
    for (int i = 0; i < 4; ++i)
#pragma unroll
      for (int j = 0; j < 4; ++j)
        acc[i][j] = __builtin_amdgcn_mfma_f32_16x16x32_bf16(af[i], bfr[j], acc[i][j], 0, 0, 0);
  }
  float bv[4], vsv[4], vdv[4];
#pragma unroll
  for (int j = 0; j < 4; ++j) {
    int col = h * 128 + wn + j * 16 + l15;
    bv[j] = b1[col]; vsv[j] = vs2[col]; vdv[j] = vd2[col];
  }
  int slab = h * 2 + (wn >> 6);
#pragma unroll
  for (int i = 0; i < 4; ++i)
#pragma unroll
    for (int r = 0; r < 4; ++r) {
      int lrow = wm + i * 16 + kg * 4 + r;
      int row = m0 + lrow;
      bool vrow = row < M;
      float ps = 0.f, pd = 0.f;
#pragma unroll
      for (int j = 0; j < 4; ++j) {
        float a = acc[i][j][r] + bv[j];
        a = a > 0.f ? a : __expf(a) - 1.f;   // ELU
        __bf16 xb = (__bf16)a;
        if (vrow) x1[(size_t)row * 512 + h * 128 + wn + j * 16 + l15] = xb;
        float af = (float)xb;
        ps += af * vsv[j];
        pd += af * vdv[j];
      }
      ps += __shfl_xor(ps, 1, 16); ps += __shfl_xor(ps, 2, 16);
      ps += __shfl_xor(ps, 4, 16); ps += __shfl_xor(ps, 8, 16);
      pd += __shfl_xor(pd, 1, 16); pd += __shfl_xor(pd, 2, 16);
      pd += __shfl_xor(pd, 4, 16); pd += __shfl_xor(pd, 8, 16);
      if (l15 == 0 && vrow) {
        as2p[(size_t)slab * M + row] = ps;
        ad2p[(size_t)slab * M + row] = pd;
      }
    }
}

// ---------- merge alpha2 partial slabs ----------
__global__ void merge_alpha2_kernel(const float* __restrict__ as2p, const float* __restrict__ ad2p,
                                    float* __restrict__ as2, float* __restrict__ ad2, int n) {
  int i = blockIdx.x * blockDim.x + threadIdx.x;
  if (i >= n) return;
  float s = 0.f, d = 0.f;
#pragma unroll
  for (int b = 0; b < 8; ++b) {
    s += as2p[(size_t)b * n + i];
    d += ad2p[(size_t)b * n + i];
  }
  as2[i] = s; ad2[i] = d;
}

// ---------- layer-2 denom: invW[d] = invN / sum_e w_e (CSR walk, no atomics) ----------
__global__ __launch_bounds__(256) void invw_kernel(
    const int* __restrict__ off, const int* __restrict__ csr_src,
    const float* __restrict__ as2, const float* __restrict__ ad2,
    float* __restrict__ invw, float invN, int n) {
  int d = (blockIdx.x * 256 + threadIdx.x) >> 4;
  int p = threadIdx.x & 15;
  if (d >= n) return;
  float adv = ad2[d];
  int beg = off[d], end = off[d + 1];
  float wsum = 0.f;
  for (int i = beg + p; i < end; i += 16) {
    float l = as2[csr_src[i]] + adv;
    l = l >= 0.f ? l : NEG_SLOPE * l;
    wsum += __expf(l);
  }
  wsum += __shfl_xor(wsum, 1, 16); wsum += __shfl_xor(wsum, 2, 16);
  wsum += __shfl_xor(wsum, 4, 16); wsum += __shfl_xor(wsum, 8, 16);
  if (p == 0) invw[d] = invN / wsum;
}

// ---------- layer-2 gamma scatter: edge-parallel, coalesced ei loads ----------
__global__ __launch_bounds__(256) void gamma_scatter_kernel(
    const int* __restrict__ ei, int E, int ntot,
    const float* __restrict__ as2, const float* __restrict__ ad2,
    const float* __restrict__ invw, float* __restrict__ gamma) {
  int e = blockIdx.x * 256 + threadIdx.x;
  if (e >= ntot) return;
  int s, d;
  if (e < E) { s = ei[e]; d = ei[E + e]; } else { s = d = e - E; }
  float l = as2[s] + ad2[d];
  l = l >= 0.f ? l : NEG_SLOPE * l;
  atomicAdd(&gamma[s], __expf(l) * invw[d]);
}

// ---------- weighted column sum stage 1 ----------
__global__ __launch_bounds__(256) void colsum1_kernel(const __bf16* __restrict__ x1,
                                                      const float* __restrict__ gamma,
                                                      float* __restrict__ pcol, int n) {
  __shared__ float sc[512];
  int t = threadIdx.x;
  sc[t] = 0.f; sc[t + 256] = 0.f;
  __syncthreads();
  int lane = t & 63, w = t >> 6;
  float acc[8] = {};
  for (int r = blockIdx.x * 4 + w; r < n; r += gridDim.x * 4) {
    float g = gamma[r];
    bf16x8 v = *(const bf16x8*)(x1 + (size_t)r * 512 + lane * 8);
#pragma unroll
    for (int j = 0; j < 8; ++j) acc[j] += g * (float)v[j];
  }
#pragma unroll
  for (int j = 0; j < 8; ++j) atomicAdd(&sc[lane * 8 + j], acc[j]);
  __syncthreads();
  pcol[(size_t)blockIdx.x * 512 + t] = sc[t];
  pcol[(size_t)blockIdx.x * 512 + 256 + t] = sc[t + 256];
}

// ---------- final: reduce pcol slice + matvec; out[c] = colsum . W2[:,c] + b2[c] ----------
__global__ __launch_bounds__(256) void final_kernel(const float* __restrict__ pcol,
                                                    const float* __restrict__ W2,
                                                    const float* __restrict__ b2,
                                                    float* __restrict__ out, int nb) {
  __shared__ float tmp[256];
  __shared__ float cs[64];
  int t = threadIdx.x;
  int k0 = blockIdx.x * 64;          // 8 blocks x 64 k
  int kl = t & 63, rg = t >> 6;      // 4 row-groups
  float a = 0.f;
  for (int b = rg; b < nb; b += 4) a += pcol[(size_t)b * 512 + k0 + kl];
  tmp[t] = a;
  __syncthreads();
  if (t < 64) cs[t] = tmp[t] + tmp[t + 64] + tmp[t + 128] + tmp[t + 192];
  __syncthreads();
  int c = t;
  float acc = 0.f;
#pragma unroll 4
  for (int k = 0; k < 64; ++k) acc += cs[k] * W2[(size_t)(k0 + k) * 256 + c];
  if (blockIdx.x == 0) acc += b2[c];
  atomicAdd(&out[c], acc);
}

__global__ void bcast_kernel(float* __restrict__ dout, int total) {
  int i = blockIdx.x * blockDim.x + threadIdx.x;
  if (i >= 256 && i < total) dout[i] = dout[i & 255];
}

// ---------- host ----------
extern "C" void kernel_launch(void* const* d_in, const int* in_sizes, int n_in,
                              void* d_out, int out_size, void* d_ws, size_t ws_size,
                              hipStream_t stream) {
  const int* ei = (const int*)d_in[0];
  const float* emb = (const float*)d_in[1];
  const float* W1 = (const float*)d_in[2];
  const float* as1w = (const float*)d_in[3];
  const float* ad1w = (const float*)d_in[4];
  const float* b1 = (const float*)d_in[5];
  const float* W2 = (const float*)d_in[6];
  const float* as2w = (const float*)d_in[7];
  const float* ad2w = (const float*)d_in[8];
  const float* b2 = (const float*)d_in[9];
  float* out = (float*)d_out;

  const int E = in_sizes[0] / 2;
  const int N = in_sizes[1] / 64;
  const int NT = E + N;
  const int CS1 = 1024;   // colsum stage-1 blocks

  char* ws = (char*)d_ws;
  size_t o = 0;
  auto alloc = [&](size_t bytes) { size_t r = o; o += (bytes + 255) & ~(size_t)255; return r; };
  __bf16* embb  = (__bf16*)(ws + alloc((size_t)N * 64 * 2));
  __bf16* aggE  = (__bf16*)(ws + alloc((size_t)N * 256 * 2));
  __bf16* x1    = (__bf16*)(ws + alloc((size_t)N * 512 * 2));
  __bf16* W1T   = (__bf16*)(ws + alloc((size_t)512 * 64 * 2));
  float* as1    = (float*)(ws + alloc((size_t)N * 4 * 4));
  float* ad1    = (float*)(ws + alloc((size_t)N * 4 * 4));
  float* as2    = (float*)(ws + alloc((size_t)N * 4));
  float* ad2    = (float*)(ws + alloc((size_t)N * 4));
  float* as2p   = (float*)(ws + alloc((size_t)8 * N * 4));
  float* ad2p   = (float*)(ws + alloc((size_t)8 * N * 4));
  float* pcol   = (float*)(ws + alloc((size_t)CS1 * 512 * 4));
  float* invw   = (float*)(ws + alloc((size_t)N * 4));
  size_t zbeg = o;
  int* deg      = (int*)(ws + alloc((size_t)N * 4));
  int* cursor   = (int*)(ws + alloc((size_t)N * 4));
  float* gamma  = (float*)(ws + alloc((size_t)N * 4));
  size_t zend = o;
  int* off      = (int*)(ws + alloc((size_t)(N + 1) * 4));
  int* partial  = (int*)(ws + alloc(256 * 4));
  int* csr_src  = (int*)(ws + alloc((size_t)NT * 4));
  float* Vs1    = (float*)(ws + alloc(64 * 4 * 4));
  float* Vd1    = (float*)(ws + alloc(64 * 4 * 4));
  float* vs2    = (float*)(ws + alloc(512 * 4));
  float* vd2    = (float*)(ws + alloc(512 * 4));

  hipMemsetAsync(ws + zbeg, 0, zend - zbeg, stream);
  hipMemsetAsync(d_out, 0, (size_t)out_size * 4, stream);

  // merged independent prep (v1 | v2 | transpose | deg)
  int degBlocks = (E / 4 + 255) / 256;
  prep_all_kernel<<<131 + degBlocks, 256, 0, stream>>>(W1, as1w, ad1w, W2, as2w, ad2w, ei, E,
                                                       Vs1, Vd1, vs2, vd2, W1T, deg);
  int nb = (N + 255) / 256;
  emb_prep_kernel<<<nb, 256, 0, stream>>>(emb, Vs1, Vd1, embb, as1, ad1, N);

  // CSR: reduce -> final(inline prefix) -> scatter(+selfloop)
  scan_reduce_kernel<<<nb, 256, 0, stream>>>(deg, partial, N);
  scan_final_kernel<<<nb, 256, 0, stream>>>(deg, partial, off, N);
  int scatterBlocks = (E + 255) / 256;
  scatter_kernel<<<scatterBlocks + nb, 256, 0, stream>>>(ei, E, off, cursor, csr_src, N,
                                                         scatterBlocks);

  // layer 1
  agg_emb_kernel<<<N / 2, 128, 0, stream>>>(off, csr_src, embb, as1, ad1, aggE);
  dim3 g1((N + 127) / 128, 1, 4);
  gemm1p_kernel<<<g1, 256, 0, stream>>>(aggE, W1T, b1, vs2, vd2, x1, as2p, ad2p, N);
  merge_alpha2_kernel<<<nb, 256, 0, stream>>>(as2p, ad2p, as2, ad2, N);

  // layer 2 collapsed: invW (CSR walk) -> edge-parallel gamma scatter -> colsum -> final
  invw_kernel<<<(N * 16 + 255) / 256, 256, 0, stream>>>(off, csr_src, as2, ad2, invw,
                                                        1.0f / (float)N, N);
  gamma_scatter_kernel<<<(NT + 255) / 256, 256, 0, stream>>>(ei, E, NT, as2, ad2, invw, gamma);
  colsum1_kernel<<<CS1, 256, 0, stream>>>(x1, gamma, pcol, N);
  final_kernel<<<8, 256, 0, stream>>>(pcol, W2, b2, out, CS1);

  if (out_size > 256) {
    bcast_kernel<<<(out_size + 255) / 256, 256, 0, stream>>>(out, out_size);
  }
}

// Round 10
// 284.211 us; speedup vs baseline: 1.2203x; 1.2203x over previous
//
#include <hip/hip_runtime.h>
#include <cstdint>
#include <cstddef>

#define NEG_SLOPE 0.2f

typedef __bf16 bf16x8 __attribute__((ext_vector_type(8)));
typedef __bf16 bf16x4 __attribute__((ext_vector_type(4)));
typedef float f32x4 __attribute__((ext_vector_type(4)));

// ---------- merged independent prep: prep_v1 | prep_v2 | W1 transpose | deg ----------
__global__ __launch_bounds__(256) void prep_all_kernel(
    const float* __restrict__ W1, const float* __restrict__ as1, const float* __restrict__ ad1,
    const float* __restrict__ W2, const float* __restrict__ as2, const float* __restrict__ ad2,
    const int* __restrict__ ei, int E,
    float* __restrict__ Vs, float* __restrict__ Vd,
    float* __restrict__ vs2, float* __restrict__ vd2,
    __bf16* __restrict__ W1T, int* __restrict__ deg) {
  int bid = blockIdx.x, tid = threadIdx.x;
  if (bid == 0) {
    int k = tid >> 2, h = tid & 3;
    const float* w = W1 + k * 512 + h * 128;
    const float* a1 = as1 + h * 128;
    const float* a2 = ad1 + h * 128;
    float s = 0.f, d = 0.f;
    for (int c = 0; c < 128; ++c) { float wv = w[c]; s += wv * a1[c]; d += wv * a2[c]; }
    Vs[k * 4 + h] = s; Vd[k * 4 + h] = d;
  } else if (bid <= 2) {
    int k = (bid - 1) * 256 + tid;
    if (k < 512) {
      const float* w = W2 + k * 256;
      float s = 0.f, d = 0.f;
      for (int c = 0; c < 256; ++c) { float wv = w[c]; s += wv * as2[c]; d += wv * ad2[c]; }
      vs2[k] = s; vd2[k] = d;
    }
  } else if (bid <= 130) {
    int idx = (bid - 3) * 256 + tid;   // < 32768
    int n = idx >> 6, k = idx & 63;    // W1T[n*64+k] = W1[k*512+n]
    W1T[idx] = (__bf16)W1[(size_t)k * 512 + n];
  } else {
    int t = (bid - 131) * 256 + tid;
    int base = t * 4;
    if (base >= E) return;
    if (base + 4 <= E) {
      int4 d4 = *(const int4*)(ei + E + base);
      atomicAdd(&deg[d4.x], 1);
      atomicAdd(&deg[d4.y], 1);
      atomicAdd(&deg[d4.z], 1);
      atomicAdd(&deg[d4.w], 1);
    } else {
      for (int e = base; e < E; ++e) atomicAdd(&deg[ei[E + e]], 1);
    }
  }
}

// ---------- fused emb -> bf16 + alpha1 ----------
__global__ void emb_prep_kernel(const float* __restrict__ emb, const float* __restrict__ Vs,
                                const float* __restrict__ Vd, __bf16* __restrict__ embb,
                                float* __restrict__ as_, float* __restrict__ ad_, int n) {
  __shared__ float sVs[256];
  __shared__ float sVd[256];
  for (int i = threadIdx.x; i < 256; i += blockDim.x) { sVs[i] = Vs[i]; sVd[i] = Vd[i]; }
  __syncthreads();
  int node = blockIdx.x * blockDim.x + threadIdx.x;
  if (node >= n) return;
  const float* xr = emb + (size_t)node * 64;
  __bf16* br = embb + (size_t)node * 64;
  float accs[4] = {}, accd[4] = {};
  for (int k = 0; k < 64; k += 4) {
    float4 xv = *(const float4*)(xr + k);
    bf16x4 o;
    o[0] = (__bf16)xv.x; o[1] = (__bf16)xv.y; o[2] = (__bf16)xv.z; o[3] = (__bf16)xv.w;
    *(bf16x4*)(br + k) = o;
#pragma unroll
    for (int h = 0; h < 4; ++h) {
      accs[h] += xv.x * sVs[(k + 0) * 4 + h] + xv.y * sVs[(k + 1) * 4 + h] +
                 xv.z * sVs[(k + 2) * 4 + h] + xv.w * sVs[(k + 3) * 4 + h];
      accd[h] += xv.x * sVd[(k + 0) * 4 + h] + xv.y * sVd[(k + 1) * 4 + h] +
                 xv.z * sVd[(k + 2) * 4 + h] + xv.w * sVd[(k + 3) * 4 + h];
    }
  }
#pragma unroll
  for (int h = 0; h < 4; ++h) {
    as_[(size_t)node * 4 + h] = accs[h];
    ad_[(size_t)node * 4 + h] = accd[h];
  }
}

// ---------- CSR scan ----------
__global__ void scan_reduce_kernel(const int* __restrict__ deg, int* __restrict__ partial, int n) {
  __shared__ int ws[4];
  int i = blockIdx.x * 256 + threadIdx.x;
  int v = (i < n) ? deg[i] + 1 : 0;
  int lane = threadIdx.x & 63, w = threadIdx.x >> 6;
#pragma unroll
  for (int s = 32; s; s >>= 1) v += __shfl_down(v, s, 64);
  if (lane == 0) ws[w] = v;
  __syncthreads();
  if (threadIdx.x == 0) partial[blockIdx.x] = ws[0] + ws[1] + ws[2] + ws[3];
}

__global__ void scan_final_kernel(const int* __restrict__ deg, const int* __restrict__ partial,
                                  int* __restrict__ off, int n) {
  __shared__ int ws[4];
  __shared__ int bsum[4];
  __shared__ int sbase;
  int b = blockIdx.x, t = threadIdx.x;
  int lane = t & 63, w = t >> 6;
  int ps = (t < b) ? partial[t] : 0;    // b <= 255 assumed
#pragma unroll
  for (int s = 32; s; s >>= 1) ps += __shfl_down(ps, s, 64);
  if (lane == 0) bsum[w] = ps;
  __syncthreads();
  if (t == 0) sbase = bsum[0] + bsum[1] + bsum[2] + bsum[3];
  int i = b * 256 + t;
  int v = (i < n) ? deg[i] + 1 : 0;
  int x = v;
#pragma unroll
  for (int s = 1; s < 64; s <<= 1) {
    int tt = __shfl_up(x, s, 64);
    if (lane >= s) x += tt;
  }
  if (lane == 63) ws[w] = x;
  __syncthreads();
  int wo = 0;
  for (int k = 0; k < w; ++k) wo += ws[k];
  int base = sbase;
  if (i < n) off[i] = base + wo + x - v;
  if (i == n - 1) off[n] = base + wo + x;
}

// ---------- scatter real edges + self-loop tail slot ----------
__global__ void scatter_kernel(const int* __restrict__ ei, int E, const int* __restrict__ off,
                               int* __restrict__ cursor, int* __restrict__ csr_src, int n,
                               int scatterBlocks) {
  if ((int)blockIdx.x < scatterBlocks) {
    int e = blockIdx.x * 256 + threadIdx.x;
    if (e >= E) return;
    int s = ei[e], d = ei[E + e];
    int p = atomicAdd(&cursor[d], 1);
    csr_src[off[d] + p] = s;
  } else {
    int d = (blockIdx.x - scatterBlocks) * 256 + threadIdx.x;
    if (d < n) csr_src[off[d + 1] - 1] = d;
  }
}

// ---------- layer-1 aggregation in EMBEDDING space, 8 edges in flight ----------
__global__ __launch_bounds__(128) void agg_emb_kernel(
    const int* __restrict__ off, const int* __restrict__ csr_src,
    const __bf16* __restrict__ embb, const float* __restrict__ as_,
    const float* __restrict__ ad_, __bf16* __restrict__ aggE) {
  int d = blockIdx.x * 2 + (threadIdx.x >> 6);
  int lane = threadIdx.x & 63;
  int g = lane >> 3, p = lane & 7;
  float4 adv = *(const float4*)(ad_ + (size_t)d * 4);
  float acc[4][8] = {};   // [head][chan]
  float wsum[4] = {};
  int beg = off[d], end = off[d + 1];
  for (int i0 = beg; i0 < end; i0 += 8) {
    int i = i0 + g;
    float vm = (i < end) ? 1.f : 0.f;
    int idx = (i < end) ? i : (end - 1);
    int s = csr_src[idx];
    float4 asv = *(const float4*)(as_ + (size_t)s * 4);
    float l0 = asv.x + adv.x; l0 = l0 >= 0.f ? l0 : NEG_SLOPE * l0;
    float l1 = asv.y + adv.y; l1 = l1 >= 0.f ? l1 : NEG_SLOPE * l1;
    float l2 = asv.z + adv.z; l2 = l2 >= 0.f ? l2 : NEG_SLOPE * l2;
    float l3 = asv.w + adv.w; l3 = l3 >= 0.f ? l3 : NEG_SLOPE * l3;
    float w0 = __expf(l0) * vm, w1 = __expf(l1) * vm;
    float w2 = __expf(l2) * vm, w3 = __expf(l3) * vm;
    bf16x8 v = *(const bf16x8*)(embb + (size_t)s * 64 + p * 8);
    float f[8];
#pragma unroll
    for (int c = 0; c < 8; ++c) f[c] = (float)v[c];
#pragma unroll
    for (int c = 0; c < 8; ++c) {
      acc[0][c] += w0 * f[c];
      acc[1][c] += w1 * f[c];
      acc[2][c] += w2 * f[c];
      acc[3][c] += w3 * f[c];
    }
    wsum[0] += w0; wsum[1] += w1; wsum[2] += w2; wsum[3] += w3;
  }
#pragma unroll
  for (int h = 0; h < 4; ++h) {
#pragma unroll
    for (int c = 0; c < 8; ++c) {
      acc[h][c] += __shfl_xor(acc[h][c], 8, 64);
      acc[h][c] += __shfl_xor(acc[h][c], 16, 64);
      acc[h][c] += __shfl_xor(acc[h][c], 32, 64);
    }
    wsum[h] += __shfl_xor(wsum[h], 8, 64);
    wsum[h] += __shfl_xor(wsum[h], 16, 64);
    wsum[h] += __shfl_xor(wsum[h], 32, 64);
  }
  if (g == 0) {
#pragma unroll
    for (int h = 0; h < 4; ++h) {
      float inv = 1.0f / wsum[h];
      bf16x8 o;
#pragma unroll
      for (int c = 0; c < 8; ++c) o[c] = (__bf16)(acc[h][c] * inv);
      *(bf16x8*)(aggE + (size_t)d * 256 + h * 64 + p * 8) = o;
    }
  }
}

// ---------- reconstruct x1 (per-head MFMA GEMM + bias + ELU) with fused alpha2 partials ----------
__global__ __launch_bounds__(256) void gemm1p_kernel(const __bf16* __restrict__ aggE,
                                                     const __bf16* __restrict__ W1T,
                                                     const float* __restrict__ b1,
                                                     const float* __restrict__ vs2,
                                                     const float* __restrict__ vd2,
                                                     __bf16* __restrict__ x1,
                                                     float* __restrict__ as2p,
                                                     float* __restrict__ ad2p, int M) {
  __shared__ __bf16 Asl[128 * 72];
  __shared__ __bf16 Bsl[128 * 72];
  int tid = threadIdx.x;
  int h = blockIdx.z;
  int m0 = blockIdx.x * 128;
  int wave = tid >> 6, lane = tid & 63;
  int wm = (wave >> 1) * 64, wn = (wave & 1) * 64;
  int l15 = lane & 15, kg = lane >> 4;
#pragma unroll
  for (int i = 0; i < 4; ++i) {
    int c = tid + i * 256;
    int row = c >> 3, off = (c & 7) * 8;
    bf16x8 va = {};
    int gr = m0 + row;
    if (gr < M) va = *(const bf16x8*)(aggE + (size_t)gr * 256 + h * 64 + off);
    *(bf16x8*)(&Asl[row * 72 + off]) = va;
    bf16x8 vb = *(const bf16x8*)(W1T + ((size_t)h * 128 + row) * 64 + off);
    *(bf16x8*)(&Bsl[row * 72 + off]) = vb;
  }
  __syncthreads();
  f32x4 acc[4][4] = {};
#pragma unroll
  for (int ks = 0; ks < 2; ++ks) {
    bf16x8 af[4], bfr[4];
#pragma unroll
    for (int f = 0; f < 4; ++f) {
      af[f]  = *(const bf16x8*)(&Asl[(wm + f * 16 + l15) * 72 + kg * 8 + ks * 32]);
      bfr[f] = *(const bf16x8*)(&Bsl[(wn + f * 16 + l15) * 72 + kg * 8 + ks * 32]);
    }
#pragma unroll
    for (int i = 0; i < 4; ++i)
#pragma unroll
      for (int j = 0; j < 4; ++j)
        acc[i][j] = __builtin_amdgcn_mfma_f32_16x16x32_bf16(af[i], bfr[j], acc[i][j], 0, 0, 0);
  }
  float bv[4], vsv[4], vdv[4];
#pragma unroll
  for (int j = 0; j < 4; ++j) {
    int col = h * 128 + wn + j * 16 + l15;
    bv[j] = b1[col]; vsv[j] = vs2[col]; vdv[j] = vd2[col];
  }
  int slab = h * 2 + (wn >> 6);
#pragma unroll
  for (int i = 0; i < 4; ++i)
#pragma unroll
    for (int r = 0; r < 4; ++r) {
      int lrow = wm + i * 16 + kg * 4 + r;
      int row = m0 + lrow;
      bool vrow = row < M;
      float ps = 0.f, pd = 0.f;
#pragma unroll
      for (int j = 0; j < 4; ++j) {
        float a = acc[i][j][r] + bv[j];
        a = a > 0.f ? a : __expf(a) - 1.f;   // ELU
        __bf16 xb = (__bf16)a;
        if (vrow) x1[(size_t)row * 512 + h * 128 + wn + j * 16 + l15] = xb;
        float af = (float)xb;
        ps += af * vsv[j];
        pd += af * vdv[j];
      }
      ps += __shfl_xor(ps, 1, 16); ps += __shfl_xor(ps, 2, 16);
      ps += __shfl_xor(ps, 4, 16); ps += __shfl_xor(ps, 8, 16);
      pd += __shfl_xor(pd, 1, 16); pd += __shfl_xor(pd, 2, 16);
      pd += __shfl_xor(pd, 4, 16); pd += __shfl_xor(pd, 8, 16);
      if (l15 == 0 && vrow) {
        as2p[(size_t)slab * M + row] = ps;
        ad2p[(size_t)slab * M + row] = pd;
      }
    }
}

// ---------- merge alpha2 partial slabs ----------
__global__ void merge_alpha2_kernel(const float* __restrict__ as2p, const float* __restrict__ ad2p,
                                    float* __restrict__ as2, float* __restrict__ ad2, int n) {
  int i = blockIdx.x * blockDim.x + threadIdx.x;
  if (i >= n) return;
  float s = 0.f, d = 0.f;
#pragma unroll
  for (int b = 0; b < 8; ++b) {
    s += as2p[(size_t)b * n + i];
    d += ad2p[(size_t)b * n + i];
  }
  as2[i] = s; ad2[i] = d;
}

// ---------- layer-2 denom: invW[d] = invN / sum_e w_e (CSR walk, no atomics) ----------
__global__ __launch_bounds__(256) void invw_kernel(
    const int* __restrict__ off, const int* __restrict__ csr_src,
    const float* __restrict__ as2, const float* __restrict__ ad2,
    float* __restrict__ invw, float invN, int n) {
  int d = (blockIdx.x * 256 + threadIdx.x) >> 4;
  int p = threadIdx.x & 15;
  if (d >= n) return;
  float adv = ad2[d];
  int beg = off[d], end = off[d + 1];
  float wsum = 0.f;
  for (int i = beg + p; i < end; i += 16) {
    float l = as2[csr_src[i]] + adv;
    l = l >= 0.f ? l : NEG_SLOPE * l;
    wsum += __expf(l);
  }
  wsum += __shfl_xor(wsum, 1, 16); wsum += __shfl_xor(wsum, 2, 16);
  wsum += __shfl_xor(wsum, 4, 16); wsum += __shfl_xor(wsum, 8, 16);
  if (p == 0) invw[d] = invN / wsum;
}

// ---------- layer-2 gamma scatter: edge-parallel, coalesced ei loads ----------
__global__ __launch_bounds__(256) void gamma_scatter_kernel(
    const int* __restrict__ ei, int E, int ntot,
    const float* __restrict__ as2, const float* __restrict__ ad2,
    const float* __restrict__ invw, float* __restrict__ gamma) {
  int e = blockIdx.x * 256 + threadIdx.x;
  if (e >= ntot) return;
  int s, d;
  if (e < E) { s = ei[e]; d = ei[E + e]; } else { s = d = e - E; }
  float l = as2[s] + ad2[d];
  l = l >= 0.f ? l : NEG_SLOPE * l;
  atomicAdd(&gamma[s], __expf(l) * invw[d]);
}

// ---------- weighted column sum stage 1 ----------
__global__ __launch_bounds__(256) void colsum1_kernel(const __bf16* __restrict__ x1,
                                                      const float* __restrict__ gamma,
                                                      float* __restrict__ pcol, int n) {
  __shared__ float sc[512];
  int t = threadIdx.x;
  sc[t] = 0.f; sc[t + 256] = 0.f;
  __syncthreads();
  int lane = t & 63, w = t >> 6;
  float acc[8] = {};
  for (int r = blockIdx.x * 4 + w; r < n; r += gridDim.x * 4) {
    float g = gamma[r];
    bf16x8 v = *(const bf16x8*)(x1 + (size_t)r * 512 + lane * 8);
#pragma unroll
    for (int j = 0; j < 8; ++j) acc[j] += g * (float)v[j];
  }
#pragma unroll
  for (int j = 0; j < 8; ++j) atomicAdd(&sc[lane * 8 + j], acc[j]);
  __syncthreads();
  pcol[(size_t)blockIdx.x * 512 + t] = sc[t];
  pcol[(size_t)blockIdx.x * 512 + 256 + t] = sc[t + 256];
}

// stage 2: parallel block-sliced reduction; block b sums rows [b*16, b*16+16)
__global__ __launch_bounds__(256) void colsum2_kernel(const float* __restrict__ pcol,
                                                      float* __restrict__ colsum, int nb) {
  int c = threadIdx.x;
  int b0 = blockIdx.x * 16;
  float a0 = 0.f, a1 = 0.f;
#pragma unroll 4
  for (int b = b0; b < b0 + 16; ++b) {
    if (b < nb) {
      a0 += pcol[(size_t)b * 512 + c];
      a1 += pcol[(size_t)b * 512 + 256 + c];
    }
  }
  atomicAdd(&colsum[c], a0);
  atomicAdd(&colsum[c + 256], a1);
}

// ---------- final matvec: out[c] = colsum . W2[:,c] + b2[c] ----------
__global__ void final_kernel(const float* __restrict__ colsum, const float* __restrict__ W2,
                             const float* __restrict__ b2, float* __restrict__ out) {
  int c = threadIdx.x;  // 256
  int k0 = blockIdx.x * 64;  // 8 blocks x 64 k
  float acc = 0.f;
  for (int k = k0; k < k0 + 64; ++k) acc += colsum[k] * W2[(size_t)k * 256 + c];
  if (blockIdx.x == 0) acc += b2[c];
  atomicAdd(&out[c], acc);
}

__global__ void bcast_kernel(float* __restrict__ dout, int total) {
  int i = blockIdx.x * blockDim.x + threadIdx.x;
  if (i >= 256 && i < total) dout[i] = dout[i & 255];
}

// ---------- host ----------
extern "C" void kernel_launch(void* const* d_in, const int* in_sizes, int n_in,
                              void* d_out, int out_size, void* d_ws, size_t ws_size,
                              hipStream_t stream) {
  const int* ei = (const int*)d_in[0];
  const float* emb = (const float*)d_in[1];
  const float* W1 = (const float*)d_in[2];
  const float* as1w = (const float*)d_in[3];
  const float* ad1w = (const float*)d_in[4];
  const float* b1 = (const float*)d_in[5];
  const float* W2 = (const float*)d_in[6];
  const float* as2w = (const float*)d_in[7];
  const float* ad2w = (const float*)d_in[8];
  const float* b2 = (const float*)d_in[9];
  float* out = (float*)d_out;

  const int E = in_sizes[0] / 2;
  const int N = in_sizes[1] / 64;
  const int NT = E + N;
  const int CS1 = 1024;   // colsum stage-1 blocks

  char* ws = (char*)d_ws;
  size_t o = 0;
  auto alloc = [&](size_t bytes) { size_t r = o; o += (bytes + 255) & ~(size_t)255; return r; };
  __bf16* embb  = (__bf16*)(ws + alloc((size_t)N * 64 * 2));
  __bf16* aggE  = (__bf16*)(ws + alloc((size_t)N * 256 * 2));
  __bf16* x1    = (__bf16*)(ws + alloc((size_t)N * 512 * 2));
  __bf16* W1T   = (__bf16*)(ws + alloc((size_t)512 * 64 * 2));
  float* as1    = (float*)(ws + alloc((size_t)N * 4 * 4));
  float* ad1    = (float*)(ws + alloc((size_t)N * 4 * 4));
  float* as2    = (float*)(ws + alloc((size_t)N * 4));
  float* ad2    = (float*)(ws + alloc((size_t)N * 4));
  float* as2p   = (float*)(ws + alloc((size_t)8 * N * 4));
  float* ad2p   = (float*)(ws + alloc((size_t)8 * N * 4));
  float* pcol   = (float*)(ws + alloc((size_t)CS1 * 512 * 4));
  float* invw   = (float*)(ws + alloc((size_t)N * 4));
  size_t zbeg = o;
  int* deg      = (int*)(ws + alloc((size_t)N * 4));
  int* cursor   = (int*)(ws + alloc((size_t)N * 4));
  float* gamma  = (float*)(ws + alloc((size_t)N * 4));
  float* colsum = (float*)(ws + alloc(512 * 4));
  size_t zend = o;
  int* off      = (int*)(ws + alloc((size_t)(N + 1) * 4));
  int* partial  = (int*)(ws + alloc(256 * 4));
  int* csr_src  = (int*)(ws + alloc((size_t)NT * 4));
  float* Vs1    = (float*)(ws + alloc(64 * 4 * 4));
  float* Vd1    = (float*)(ws + alloc(64 * 4 * 4));
  float* vs2    = (float*)(ws + alloc(512 * 4));
  float* vd2    = (float*)(ws + alloc(512 * 4));

  hipMemsetAsync(ws + zbeg, 0, zend - zbeg, stream);
  hipMemsetAsync(d_out, 0, (size_t)out_size * 4, stream);

  // merged independent prep (v1 | v2 | transpose | deg)
  int degBlocks = (E / 4 + 255) / 256;
  prep_all_kernel<<<131 + degBlocks, 256, 0, stream>>>(W1, as1w, ad1w, W2, as2w, ad2w, ei, E,
                                                       Vs1, Vd1, vs2, vd2, W1T, deg);
  int nb = (N + 255) / 256;
  emb_prep_kernel<<<nb, 256, 0, stream>>>(emb, Vs1, Vd1, embb, as1, ad1, N);

  // CSR: reduce -> final(inline prefix) -> scatter(+selfloop)
  scan_reduce_kernel<<<nb, 256, 0, stream>>>(deg, partial, N);
  scan_final_kernel<<<nb, 256, 0, stream>>>(deg, partial, off, N);
  int scatterBlocks = (E + 255) / 256;
  scatter_kernel<<<scatterBlocks + nb, 256, 0, stream>>>(ei, E, off, cursor, csr_src, N,
                                                         scatterBlocks);

  // layer 1
  agg_emb_kernel<<<N / 2, 128, 0, stream>>>(off, csr_src, embb, as1, ad1, aggE);
  dim3 g1((N + 127) / 128, 1, 4);
  gemm1p_kernel<<<g1, 256, 0, stream>>>(aggE, W1T, b1, vs2, vd2, x1, as2p, ad2p, N);
  merge_alpha2_kernel<<<nb, 256, 0, stream>>>(as2p, ad2p, as2, ad2, N);

  // layer 2 collapsed: invW -> edge-parallel gamma scatter -> colsum (2 stages) -> matvec
  invw_kernel<<<(N * 16 + 255) / 256, 256, 0, stream>>>(off, csr_src, as2, ad2, invw,
                                                        1.0f / (float)N, N);
  gamma_scatter_kernel<<<(NT + 255) / 256, 256, 0, stream>>>(ei, E, NT, as2, ad2, invw, gamma);
  colsum1_kernel<<<CS1, 256, 0, stream>>>(x1, gamma, pcol, N);
  colsum2_kernel<<<CS1 / 16, 256, 0, stream>>>(pcol, colsum, CS1);
  final_kernel<<<8, 256, 0, stream>>>(colsum, W2, b2, out);

  if (out_size > 256) {
    bcast_kernel<<<(out_size + 255) / 256, 256, 0, stream>>>(out, out_size);
  }
}

// Round 11
// 259.318 us; speedup vs baseline: 1.3375x; 1.0960x over previous
//
#include <hip/hip_runtime.h>
#include <cstdint>
#include <cstddef>

#define NEG_SLOPE 0.2f

typedef __bf16 bf16x8 __attribute__((ext_vector_type(8)));
typedef __bf16 bf16x4 __attribute__((ext_vector_type(4)));
typedef float f32x4 __attribute__((ext_vector_type(4)));

// ---------- merged independent prep: prep_v1 | prep_v2 | W1 transpose | deg ----------
__global__ __launch_bounds__(256) void prep_all_kernel(
    const float* __restrict__ W1, const float* __restrict__ as1, const float* __restrict__ ad1,
    const float* __restrict__ W2, const float* __restrict__ as2, const float* __restrict__ ad2,
    const int* __restrict__ ei, int E,
    float* __restrict__ Vs, float* __restrict__ Vd,
    float* __restrict__ vs2, float* __restrict__ vd2,
    __bf16* __restrict__ W1T, int* __restrict__ deg) {
  int bid = blockIdx.x, tid = threadIdx.x;
  if (bid == 0) {
    int k = tid >> 2, h = tid & 3;
    const float* w = W1 + k * 512 + h * 128;
    const float* a1 = as1 + h * 128;
    const float* a2 = ad1 + h * 128;
    float s = 0.f, d = 0.f;
    for (int c = 0; c < 128; ++c) { float wv = w[c]; s += wv * a1[c]; d += wv * a2[c]; }
    Vs[k * 4 + h] = s; Vd[k * 4 + h] = d;
  } else if (bid <= 2) {
    int k = (bid - 1) * 256 + tid;
    if (k < 512) {
      const float* w = W2 + k * 256;
      float s = 0.f, d = 0.f;
      for (int c = 0; c < 256; ++c) { float wv = w[c]; s += wv * as2[c]; d += wv * ad2[c]; }
      vs2[k] = s; vd2[k] = d;
    }
  } else if (bid <= 130) {
    int idx = (bid - 3) * 256 + tid;   // < 32768
    int n = idx >> 6, k = idx & 63;    // W1T[n*64+k] = W1[k*512+n]
    W1T[idx] = (__bf16)W1[(size_t)k * 512 + n];
  } else {
    int t = (bid - 131) * 256 + tid;
    int base = t * 4;
    if (base >= E) return;
    if (base + 4 <= E) {
      int4 d4 = *(const int4*)(ei + E + base);
      atomicAdd(&deg[d4.x], 1);
      atomicAdd(&deg[d4.y], 1);
      atomicAdd(&deg[d4.z], 1);
      atomicAdd(&deg[d4.w], 1);
    } else {
      for (int e = base; e < E; ++e) atomicAdd(&deg[ei[E + e]], 1);
    }
  }
}

// ---------- fused emb -> bf16 + alpha1 ----------
__global__ void emb_prep_kernel(const float* __restrict__ emb, const float* __restrict__ Vs,
                                const float* __restrict__ Vd, __bf16* __restrict__ embb,
                                float* __restrict__ as_, float* __restrict__ ad_, int n) {
  __shared__ float sVs[256];
  __shared__ float sVd[256];
  for (int i = threadIdx.x; i < 256; i += blockDim.x) { sVs[i] = Vs[i]; sVd[i] = Vd[i]; }
  __syncthreads();
  int node = blockIdx.x * blockDim.x + threadIdx.x;
  if (node >= n) return;
  const float* xr = emb + (size_t)node * 64;
  __bf16* br = embb + (size_t)node * 64;
  float accs[4] = {}, accd[4] = {};
  for (int k = 0; k < 64; k += 4) {
    float4 xv = *(const float4*)(xr + k);
    bf16x4 o;
    o[0] = (__bf16)xv.x; o[1] = (__bf16)xv.y; o[2] = (__bf16)xv.z; o[3] = (__bf16)xv.w;
    *(bf16x4*)(br + k) = o;
#pragma unroll
    for (int h = 0; h < 4; ++h) {
      accs[h] += xv.x * sVs[(k + 0) * 4 + h] + xv.y * sVs[(k + 1) * 4 + h] +
                 xv.z * sVs[(k + 2) * 4 + h] + xv.w * sVs[(k + 3) * 4 + h];
      accd[h] += xv.x * sVd[(k + 0) * 4 + h] + xv.y * sVd[(k + 1) * 4 + h] +
                 xv.z * sVd[(k + 2) * 4 + h] + xv.w * sVd[(k + 3) * 4 + h];
    }
  }
#pragma unroll
  for (int h = 0; h < 4; ++h) {
    as_[(size_t)node * 4 + h] = accs[h];
    ad_[(size_t)node * 4 + h] = accd[h];
  }
}

// ---------- CSR scan ----------
__global__ void scan_reduce_kernel(const int* __restrict__ deg, int* __restrict__ partial, int n) {
  __shared__ int ws[4];
  int i = blockIdx.x * 256 + threadIdx.x;
  int v = (i < n) ? deg[i] + 1 : 0;
  int lane = threadIdx.x & 63, w = threadIdx.x >> 6;
#pragma unroll
  for (int s = 32; s; s >>= 1) v += __shfl_down(v, s, 64);
  if (lane == 0) ws[w] = v;
  __syncthreads();
  if (threadIdx.x == 0) partial[blockIdx.x] = ws[0] + ws[1] + ws[2] + ws[3];
}

__global__ void scan_final_kernel(const int* __restrict__ deg, const int* __restrict__ partial,
                                  int* __restrict__ off, int n) {
  __shared__ int ws[4];
  __shared__ int bsum[4];
  __shared__ int sbase;
  int b = blockIdx.x, t = threadIdx.x;
  int lane = t & 63, w = t >> 6;
  int ps = (t < b) ? partial[t] : 0;    // b <= 255 assumed
#pragma unroll
  for (int s = 32; s; s >>= 1) ps += __shfl_down(ps, s, 64);
  if (lane == 0) bsum[w] = ps;
  __syncthreads();
  if (t == 0) sbase = bsum[0] + bsum[1] + bsum[2] + bsum[3];
  int i = b * 256 + t;
  int v = (i < n) ? deg[i] + 1 : 0;
  int x = v;
#pragma unroll
  for (int s = 1; s < 64; s <<= 1) {
    int tt = __shfl_up(x, s, 64);
    if (lane >= s) x += tt;
  }
  if (lane == 63) ws[w] = x;
  __syncthreads();
  int wo = 0;
  for (int k = 0; k < w; ++k) wo += ws[k];
  int base = sbase;
  if (i < n) off[i] = base + wo + x - v;
  if (i == n - 1) off[n] = base + wo + x;
}

// ---------- scatter real edges + self-loop tail slot ----------
__global__ void scatter_kernel(const int* __restrict__ ei, int E, const int* __restrict__ off,
                               int* __restrict__ cursor, int* __restrict__ csr_src, int n,
                               int scatterBlocks) {
  if ((int)blockIdx.x < scatterBlocks) {
    int e = blockIdx.x * 256 + threadIdx.x;
    if (e >= E) return;
    int s = ei[e], d = ei[E + e];
    int p = atomicAdd(&cursor[d], 1);
    csr_src[off[d] + p] = s;
  } else {
    int d = (blockIdx.x - scatterBlocks) * 256 + threadIdx.x;
    if (d < n) csr_src[off[d + 1] - 1] = d;
  }
}

// ---------- layer-1 aggregation in EMBEDDING space ----------
// 4 groups x 16 lanes (cheap 40-shuffle epilogue) + manual 2-edge unroll per group
// = 8 independent gather chains in flight per wave.
__global__ __launch_bounds__(128) void agg_emb_kernel(
    const int* __restrict__ off, const int* __restrict__ csr_src,
    const __bf16* __restrict__ embb, const float* __restrict__ as_,
    const float* __restrict__ ad_, __bf16* __restrict__ aggE) {
  int d = blockIdx.x * 2 + (threadIdx.x >> 6);
  int lane = threadIdx.x & 63;
  int g = lane >> 4, p = lane & 15;
  float4 adv = *(const float4*)(ad_ + (size_t)d * 4);
  float acc[4][4] = {};   // [head][chan]
  float wsum[4] = {};
  int beg = off[d], end = off[d + 1];
  for (int i0 = beg; i0 < end; i0 += 8) {
    int iA = i0 + g, iB = i0 + 4 + g;
    int idxA = (iA < end) ? iA : (end - 1);
    int idxB = (iB < end) ? iB : (end - 1);
    float vmA = (iA < end) ? 1.f : 0.f;
    float vmB = (iB < end) ? 1.f : 0.f;
    int sA = csr_src[idxA];
    int sB = csr_src[idxB];
    float4 aA = *(const float4*)(as_ + (size_t)sA * 4);
    float4 aB = *(const float4*)(as_ + (size_t)sB * 4);
    bf16x4 vA = *(const bf16x4*)(embb + (size_t)sA * 64 + p * 4);
    bf16x4 vB = *(const bf16x4*)(embb + (size_t)sB * 64 + p * 4);
    float lA0 = aA.x + adv.x; lA0 = lA0 >= 0.f ? lA0 : NEG_SLOPE * lA0;
    float lA1 = aA.y + adv.y; lA1 = lA1 >= 0.f ? lA1 : NEG_SLOPE * lA1;
    float lA2 = aA.z + adv.z; lA2 = lA2 >= 0.f ? lA2 : NEG_SLOPE * lA2;
    float lA3 = aA.w + adv.w; lA3 = lA3 >= 0.f ? lA3 : NEG_SLOPE * lA3;
    float lB0 = aB.x + adv.x; lB0 = lB0 >= 0.f ? lB0 : NEG_SLOPE * lB0;
    float lB1 = aB.y + adv.y; lB1 = lB1 >= 0.f ? lB1 : NEG_SLOPE * lB1;
    float lB2 = aB.z + adv.z; lB2 = lB2 >= 0.f ? lB2 : NEG_SLOPE * lB2;
    float lB3 = aB.w + adv.w; lB3 = lB3 >= 0.f ? lB3 : NEG_SLOPE * lB3;
    float wA0 = __expf(lA0) * vmA, wA1 = __expf(lA1) * vmA;
    float wA2 = __expf(lA2) * vmA, wA3 = __expf(lA3) * vmA;
    float wB0 = __expf(lB0) * vmB, wB1 = __expf(lB1) * vmB;
    float wB2 = __expf(lB2) * vmB, wB3 = __expf(lB3) * vmB;
    float fA0 = (float)vA[0], fA1 = (float)vA[1], fA2 = (float)vA[2], fA3 = (float)vA[3];
    float fB0 = (float)vB[0], fB1 = (float)vB[1], fB2 = (float)vB[2], fB3 = (float)vB[3];
    acc[0][0] += wA0 * fA0; acc[0][1] += wA0 * fA1; acc[0][2] += wA0 * fA2; acc[0][3] += wA0 * fA3;
    acc[1][0] += wA1 * fA0; acc[1][1] += wA1 * fA1; acc[1][2] += wA1 * fA2; acc[1][3] += wA1 * fA3;
    acc[2][0] += wA2 * fA0; acc[2][1] += wA2 * fA1; acc[2][2] += wA2 * fA2; acc[2][3] += wA2 * fA3;
    acc[3][0] += wA3 * fA0; acc[3][1] += wA3 * fA1; acc[3][2] += wA3 * fA2; acc[3][3] += wA3 * fA3;
    acc[0][0] += wB0 * fB0; acc[0][1] += wB0 * fB1; acc[0][2] += wB0 * fB2; acc[0][3] += wB0 * fB3;
    acc[1][0] += wB1 * fB0; acc[1][1] += wB1 * fB1; acc[1][2] += wB1 * fB2; acc[1][3] += wB1 * fB3;
    acc[2][0] += wB2 * fB0; acc[2][1] += wB2 * fB1; acc[2][2] += wB2 * fB2; acc[2][3] += wB2 * fB3;
    acc[3][0] += wB3 * fB0; acc[3][1] += wB3 * fB1; acc[3][2] += wB3 * fB2; acc[3][3] += wB3 * fB3;
    wsum[0] += wA0 + wB0; wsum[1] += wA1 + wB1; wsum[2] += wA2 + wB2; wsum[3] += wA3 + wB3;
  }
  // reduce across the 4 groups (lane bits 4,5)
#pragma unroll
  for (int h = 0; h < 4; ++h) {
#pragma unroll
    for (int c = 0; c < 4; ++c) {
      acc[h][c] += __shfl_xor(acc[h][c], 16, 64);
      acc[h][c] += __shfl_xor(acc[h][c], 32, 64);
    }
    wsum[h] += __shfl_xor(wsum[h], 16, 64);
    wsum[h] += __shfl_xor(wsum[h], 32, 64);
  }
  if (g == 0) {
#pragma unroll
    for (int h = 0; h < 4; ++h) {
      float inv = 1.0f / wsum[h];
      bf16x4 o;
      o[0] = (__bf16)(acc[h][0] * inv); o[1] = (__bf16)(acc[h][1] * inv);
      o[2] = (__bf16)(acc[h][2] * inv); o[3] = (__bf16)(acc[h][3] * inv);
      *(bf16x4*)(aggE + (size_t)d * 256 + h * 64 + p * 4) = o;
    }
  }
}

// ---------- reconstruct x1 (per-head MFMA GEMM + bias + ELU) with fused alpha2 partials ----------
__global__ __launch_bounds__(256) void gemm1p_kernel(const __bf16* __restrict__ aggE,
                                                     const __bf16* __restrict__ W1T,
                                                     const float* __restrict__ b1,
                                                     const float* __restrict__ vs2,
                                                     const float* __restrict__ vd2,
                                                     __bf16* __restrict__ x1,
                                                     float* __restrict__ as2p,
                                                     float* __restrict__ ad2p, int M) {
  __shared__ __bf16 Asl[128 * 72];
  __shared__ __bf16 Bsl[128 * 72];
  int tid = threadIdx.x;
  int h = blockIdx.z;
  int m0 = blockIdx.x * 128;
  int wave = tid >> 6, lane = tid & 63;
  int wm = (wave >> 1) * 64, wn = (wave & 1) * 64;
  int l15 = lane & 15, kg = lane >> 4;
#pragma unroll
  for (int i = 0; i < 4; ++i) {
    int c = tid + i * 256;
    int row = c >> 3, off = (c & 7) * 8;
    bf16x8 va = {};
    int gr = m0 + row;
    if (gr < M) va = *(const bf16x8*)(aggE + (size_t)gr * 256 + h * 64 + off);
    *(bf16x8*)(&Asl[row * 72 + off]) = va;
    bf16x8 vb = *(const bf16x8*)(W1T + ((size_t)h * 128 + row) * 64 + off);
    *(bf16x8*)(&Bsl[row * 72 + off]) = vb;
  }
  __syncthreads();
  f32x4 acc[4][4] = {};
#pragma unroll
  for (int ks = 0; ks < 2; ++ks) {
    bf16x8 af[4], bfr[4];
#pragma unroll
    for (int f = 0; f < 4; ++f) {
      af[f]  = *(const bf16x8*)(&Asl[(wm + f * 16 + l15) * 72 + kg * 8 + ks * 32]);
      bfr[f] = *(const bf16x8*)(&Bsl[(wn + f * 16 + l15) * 72 + kg * 8 + ks * 32]);
    }
#pragma unroll
    for (int i = 0; i < 4; ++i)
#pragma unroll
      for (int j = 0; j < 4; ++j)
        acc[i][j] = __builtin_amdgcn_mfma_f32_16x16x32_bf16(af[i], bfr[j], acc[i][j], 0, 0, 0);
  }
  float bv[4], vsv[4], vdv[4];
#pragma unroll
  for (int j = 0; j < 4; ++j) {
    int col = h * 128 + wn + j * 16 + l15;
    bv[j] = b1[col]; vsv[j] = vs2[col]; vdv[j] = vd2[col];
  }
  int slab = h * 2 + (wn >> 6);
#pragma unroll
  for (int i = 0; i < 4; ++i)
#pragma unroll
    for (int r = 0; r < 4; ++r) {
      int lrow = wm + i * 16 + kg * 4 + r;
      int row = m0 + lrow;
      bool vrow = row < M;
      float ps = 0.f, pd = 0.f;
#pragma unroll
      for (int j = 0; j < 4; ++j) {
        float a = acc[i][j][r] + bv[j];
        a = a > 0.f ? a : __expf(a) - 1.f;   // ELU
        __bf16 xb = (__bf16)a;
        if (vrow) x1[(size_t)row * 512 + h * 128 + wn + j * 16 + l15] = xb;
        float af = (float)xb;
        ps += af * vsv[j];
        pd += af * vdv[j];
      }
      ps += __shfl_xor(ps, 1, 16); ps += __shfl_xor(ps, 2, 16);
      ps += __shfl_xor(ps, 4, 16); ps += __shfl_xor(ps, 8, 16);
      pd += __shfl_xor(pd, 1, 16); pd += __shfl_xor(pd, 2, 16);
      pd += __shfl_xor(pd, 4, 16); pd += __shfl_xor(pd, 8, 16);
      if (l15 == 0 && vrow) {
        as2p[(size_t)slab * M + row] = ps;
        ad2p[(size_t)slab * M + row] = pd;
      }
    }
}

// ---------- merge alpha2 partial slabs ----------
__global__ void merge_alpha2_kernel(const float* __restrict__ as2p, const float* __restrict__ ad2p,
                                    float* __restrict__ as2, float* __restrict__ ad2, int n) {
  int i = blockIdx.x * blockDim.x + threadIdx.x;
  if (i >= n) return;
  float s = 0.f, d = 0.f;
#pragma unroll
  for (int b = 0; b < 8; ++b) {
    s += as2p[(size_t)b * n + i];
    d += ad2p[(size_t)b * n + i];
  }
  as2[i] = s; ad2[i] = d;
}

// ---------- layer-2 denom: invW[d] = invN / sum_e w_e (CSR walk, no atomics) ----------
__global__ __launch_bounds__(256) void invw_kernel(
    const int* __restrict__ off, const int* __restrict__ csr_src,
    const float* __restrict__ as2, const float* __restrict__ ad2,
    float* __restrict__ invw, float invN, int n) {
  int d = (blockIdx.x * 256 + threadIdx.x) >> 4;
  int p = threadIdx.x & 15;
  if (d >= n) return;
  float adv = ad2[d];
  int beg = off[d], end = off[d + 1];
  float wsum = 0.f;
  for (int i = beg + p; i < end; i += 16) {
    float l = as2[csr_src[i]] + adv;
    l = l >= 0.f ? l : NEG_SLOPE * l;
    wsum += __expf(l);
  }
  wsum += __shfl_xor(wsum, 1, 16); wsum += __shfl_xor(wsum, 2, 16);
  wsum += __shfl_xor(wsum, 4, 16); wsum += __shfl_xor(wsum, 8, 16);
  if (p == 0) invw[d] = invN / wsum;
}

// ---------- layer-2 gamma scatter: edge-parallel, coalesced ei loads ----------
__global__ __launch_bounds__(256) void gamma_scatter_kernel(
    const int* __restrict__ ei, int E, int ntot,
    const float* __restrict__ as2, const float* __restrict__ ad2,
    const float* __restrict__ invw, float* __restrict__ gamma) {
  int e = blockIdx.x * 256 + threadIdx.x;
  if (e >= ntot) return;
  int s, d;
  if (e < E) { s = ei[e]; d = ei[E + e]; } else { s = d = e - E; }
  float l = as2[s] + ad2[d];
  l = l >= 0.f ? l : NEG_SLOPE * l;
  atomicAdd(&gamma[s], __expf(l) * invw[d]);
}

// ---------- weighted column sum stage 1 ----------
__global__ __launch_bounds__(256) void colsum1_kernel(const __bf16* __restrict__ x1,
                                                      const float* __restrict__ gamma,
                                                      float* __restrict__ pcol, int n) {
  __shared__ float sc[512];
  int t = threadIdx.x;
  sc[t] = 0.f; sc[t + 256] = 0.f;
  __syncthreads();
  int lane = t & 63, w = t >> 6;
  float acc[8] = {};
  for (int r = blockIdx.x * 4 + w; r < n; r += gridDim.x * 4) {
    float g = gamma[r];
    bf16x8 v = *(const bf16x8*)(x1 + (size_t)r * 512 + lane * 8);
#pragma unroll
    for (int j = 0; j < 8; ++j) acc[j] += g * (float)v[j];
  }
#pragma unroll
  for (int j = 0; j < 8; ++j) atomicAdd(&sc[lane * 8 + j], acc[j]);
  __syncthreads();
  pcol[(size_t)blockIdx.x * 512 + t] = sc[t];
  pcol[(size_t)blockIdx.x * 512 + 256 + t] = sc[t + 256];
}

// stage 2: parallel block-sliced reduction; block b sums rows [b*16, b*16+16)
__global__ __launch_bounds__(256) void colsum2_kernel(const float* __restrict__ pcol,
                                                      float* __restrict__ colsum, int nb) {
  int c = threadIdx.x;
  int b0 = blockIdx.x * 16;
  float a0 = 0.f, a1 = 0.f;
#pragma unroll 4
  for (int b = b0; b < b0 + 16; ++b) {
    if (b < nb) {
      a0 += pcol[(size_t)b * 512 + c];
      a1 += pcol[(size_t)b * 512 + 256 + c];
    }
  }
  atomicAdd(&colsum[c], a0);
  atomicAdd(&colsum[c + 256], a1);
}

// ---------- final matvec: out[c] = colsum . W2[:,c] + b2[c] ----------
__global__ void final_kernel(const float* __restrict__ colsum, const float* __restrict__ W2,
                             const float* __restrict__ b2, float* __restrict__ out) {
  int c = threadIdx.x;  // 256
  int k0 = blockIdx.x * 64;  // 8 blocks x 64 k
  float acc = 0.f;
  for (int k = k0; k < k0 + 64; ++k) acc += colsum[k] * W2[(size_t)k * 256 + c];
  if (blockIdx.x == 0) acc += b2[c];
  atomicAdd(&out[c], acc);
}

__global__ void bcast_kernel(float* __restrict__ dout, int total) {
  int i = blockIdx.x * blockDim.x + threadIdx.x;
  if (i >= 256 && i < total) dout[i] = dout[i & 255];
}

// ---------- host ----------
extern "C" void kernel_launch(void* const* d_in, const int* in_sizes, int n_in,
                              void* d_out, int out_size, void* d_ws, size_t ws_size,
                              hipStream_t stream) {
  const int* ei = (const int*)d_in[0];
  const float* emb = (const float*)d_in[1];
  const float* W1 = (const float*)d_in[2];
  const float* as1w = (const float*)d_in[3];
  const float* ad1w = (const float*)d_in[4];
  const float* b1 = (const float*)d_in[5];
  const float* W2 = (const float*)d_in[6];
  const float* as2w = (const float*)d_in[7];
  const float* ad2w = (const float*)d_in[8];
  const float* b2 = (const float*)d_in[9];
  float* out = (float*)d_out;

  const int E = in_sizes[0] / 2;
  const int N = in_sizes[1] / 64;
  const int NT = E + N;
  const int CS1 = 1024;   // colsum stage-1 blocks

  char* ws = (char*)d_ws;
  size_t o = 0;
  auto alloc = [&](size_t bytes) { size_t r = o; o += (bytes + 255) & ~(size_t)255; return r; };
  __bf16* embb  = (__bf16*)(ws + alloc((size_t)N * 64 * 2));
  __bf16* aggE  = (__bf16*)(ws + alloc((size_t)N * 256 * 2));
  __bf16* x1    = (__bf16*)(ws + alloc((size_t)N * 512 * 2));
  __bf16* W1T   = (__bf16*)(ws + alloc((size_t)512 * 64 * 2));
  float* as1    = (float*)(ws + alloc((size_t)N * 4 * 4));
  float* ad1    = (float*)(ws + alloc((size_t)N * 4 * 4));
  float* as2    = (float*)(ws + alloc((size_t)N * 4));
  float* ad2    = (float*)(ws + alloc((size_t)N * 4));
  float* as2p   = (float*)(ws + alloc((size_t)8 * N * 4));
  float* ad2p   = (float*)(ws + alloc((size_t)8 * N * 4));
  float* pcol   = (float*)(ws + alloc((size_t)CS1 * 512 * 4));
  float* invw   = (float*)(ws + alloc((size_t)N * 4));
  size_t zbeg = o;
  int* deg      = (int*)(ws + alloc((size_t)N * 4));
  int* cursor   = (int*)(ws + alloc((size_t)N * 4));
  float* gamma  = (float*)(ws + alloc((size_t)N * 4));
  float* colsum = (float*)(ws + alloc(512 * 4));
  size_t zend = o;
  int* off      = (int*)(ws + alloc((size_t)(N + 1) * 4));
  int* partial  = (int*)(ws + alloc(256 * 4));
  int* csr_src  = (int*)(ws + alloc((size_t)NT * 4));
  float* Vs1    = (float*)(ws + alloc(64 * 4 * 4));
  float* Vd1    = (float*)(ws + alloc(64 * 4 * 4));
  float* vs2    = (float*)(ws + alloc(512 * 4));
  float* vd2    = (float*)(ws + alloc(512 * 4));

  hipMemsetAsync(ws + zbeg, 0, zend - zbeg, stream);
  hipMemsetAsync(d_out, 0, (size_t)out_size * 4, stream);

  // merged independent prep (v1 | v2 | transpose | deg)
  int degBlocks = (E / 4 + 255) / 256;
  prep_all_kernel<<<131 + degBlocks, 256, 0, stream>>>(W1, as1w, ad1w, W2, as2w, ad2w, ei, E,
                                                       Vs1, Vd1, vs2, vd2, W1T, deg);
  int nb = (N + 255) / 256;
  emb_prep_kernel<<<nb, 256, 0, stream>>>(emb, Vs1, Vd1, embb, as1, ad1, N);

  // CSR: reduce -> final(inline prefix) -> scatter(+selfloop)
  scan_reduce_kernel<<<nb, 256, 0, stream>>>(deg, partial, N);
  scan_final_kernel<<<nb, 256, 0, stream>>>(deg, partial, off, N);
  int scatterBlocks = (E + 255) / 256;
  scatter_kernel<<<scatterBlocks + nb, 256, 0, stream>>>(ei, E, off, cursor, csr_src, N,
                                                         scatterBlocks);

  // layer 1
  agg_emb_kernel<<<N / 2, 128, 0, stream>>>(off, csr_src, embb, as1, ad1, aggE);
  dim3 g1((N + 127) / 128, 1, 4);
  gemm1p_kernel<<<g1, 256, 0, stream>>>(aggE, W1T, b1, vs2, vd2, x1, as2p, ad2p, N);
  merge_alpha2_kernel<<<nb, 256, 0, stream>>>(as2p, ad2p, as2, ad2, N);

  // layer 2 collapsed: invW -> edge-parallel gamma scatter -> colsum (2 stages) -> matvec
  invw_kernel<<<(N * 16 + 255) / 256, 256, 0, stream>>>(off, csr_src, as2, ad2, invw,
                                                        1.0f / (float)N, N);
  gamma_scatter_kernel<<<(NT + 255) / 256, 256, 0, stream>>>(ei, E, NT, as2, ad2, invw, gamma);
  colsum1_kernel<<<CS1, 256, 0, stream>>>(x1, gamma, pcol, N);
  colsum2_kernel<<<CS1 / 16, 256, 0, stream>>>(pcol, colsum, CS1);
  final_kernel<<<8, 256, 0, stream>>>(colsum, W2, b2, out);

  if (out_size > 256) {
    bcast_kernel<<<(out_size + 255) / 256, 256, 0, stream>>>(out, out_size);
  }
}

// Round 12
// 204.233 us; speedup vs baseline: 1.6982x; 1.2697x over previous
//
#include <hip/hip_runtime.h>
#include <cstdint>
#include <cstddef>

#define NEG_SLOPE 0.2f

typedef __bf16 bf16x8 __attribute__((ext_vector_type(8)));
typedef __bf16 bf16x4 __attribute__((ext_vector_type(4)));
typedef float f32x4 __attribute__((ext_vector_type(4)));

// edge i in [0,NT): real edge for i<E, self-loop (i-E, i-E) otherwise
__device__ __forceinline__ int dstKeyOf(const int* ei, int E, int i) {
  return (i < E) ? ei[E + i] : (i - E);
}
__device__ __forceinline__ int srcKeyOf(const int* ei, int E, int i) {
  return (i < E) ? ei[i] : (i - E);
}

// ---------- merged independent prep: prep_v1 | prep_v2 | W1 transpose ----------
__global__ __launch_bounds__(256) void prep_all_kernel(
    const float* __restrict__ W1, const float* __restrict__ as1, const float* __restrict__ ad1,
    const float* __restrict__ W2, const float* __restrict__ as2, const float* __restrict__ ad2,
    float* __restrict__ Vs, float* __restrict__ Vd,
    float* __restrict__ vs2, float* __restrict__ vd2,
    __bf16* __restrict__ W1T) {
  int bid = blockIdx.x, tid = threadIdx.x;
  if (bid == 0) {
    int k = tid >> 2, h = tid & 3;
    const float* w = W1 + k * 512 + h * 128;
    const float* a1 = as1 + h * 128;
    const float* a2 = ad1 + h * 128;
    float s = 0.f, d = 0.f;
    for (int c = 0; c < 128; ++c) { float wv = w[c]; s += wv * a1[c]; d += wv * a2[c]; }
    Vs[k * 4 + h] = s; Vd[k * 4 + h] = d;
  } else if (bid <= 2) {
    int k = (bid - 1) * 256 + tid;
    if (k < 512) {
      const float* w = W2 + k * 256;
      float s = 0.f, d = 0.f;
      for (int c = 0; c < 256; ++c) { float wv = w[c]; s += wv * as2[c]; d += wv * ad2[c]; }
      vs2[k] = s; vd2[k] = d;
    }
  } else {
    int idx = (bid - 3) * 256 + tid;   // < 32768
    int n = idx >> 6, k = idx & 63;    // W1T[n*64+k] = W1[k*512+n]
    W1T[idx] = (__bf16)W1[(size_t)k * 512 + n];
  }
}

// ---------- fused emb -> bf16 + alpha1 ----------
__global__ void emb_prep_kernel(const float* __restrict__ emb, const float* __restrict__ Vs,
                                const float* __restrict__ Vd, __bf16* __restrict__ embb,
                                float* __restrict__ as_, float* __restrict__ ad_, int n) {
  __shared__ float sVs[256];
  __shared__ float sVd[256];
  for (int i = threadIdx.x; i < 256; i += blockDim.x) { sVs[i] = Vs[i]; sVd[i] = Vd[i]; }
  __syncthreads();
  int node = blockIdx.x * blockDim.x + threadIdx.x;
  if (node >= n) return;
  const float* xr = emb + (size_t)node * 64;
  __bf16* br = embb + (size_t)node * 64;
  float accs[4] = {}, accd[4] = {};
  for (int k = 0; k < 64; k += 4) {
    float4 xv = *(const float4*)(xr + k);
    bf16x4 o;
    o[0] = (__bf16)xv.x; o[1] = (__bf16)xv.y; o[2] = (__bf16)xv.z; o[3] = (__bf16)xv.w;
    *(bf16x4*)(br + k) = o;
#pragma unroll
    for (int h = 0; h < 4; ++h) {
      accs[h] += xv.x * sVs[(k + 0) * 4 + h] + xv.y * sVs[(k + 1) * 4 + h] +
                 xv.z * sVs[(k + 2) * 4 + h] + xv.w * sVs[(k + 3) * 4 + h];
      accd[h] += xv.x * sVd[(k + 0) * 4 + h] + xv.y * sVd[(k + 1) * 4 + h] +
                 xv.z * sVd[(k + 2) * 4 + h] + xv.w * sVd[(k + 3) * 4 + h];
    }
  }
#pragma unroll
  for (int h = 0; h < 4; ++h) {
    as_[(size_t)node * 4 + h] = accs[h];
    ad_[(size_t)node * 4 + h] = accd[h];
  }
}

// ---------- atomic-free MSD radix sort, pass 1: per-block high-byte histograms ----------
// grid 2*nblk: blocks [0,nblk) key=dst, [nblk,2nblk) key=src. hist[(sec*256+digit)*nblk+blk]
__global__ __launch_bounds__(256) void hist_kernel(const int* __restrict__ ei, int E, int NT,
                                                   int nblk, int* __restrict__ hist) {
  __shared__ int h[256];
  int tid = threadIdx.x;
  h[tid] = 0;
  __syncthreads();
  int sec = (int)blockIdx.x >= nblk;
  int blk = blockIdx.x - sec * nblk;
  int base = blk * 1024;
#pragma unroll
  for (int j = 0; j < 4; ++j) {
    int i = base + j * 256 + tid;
    if (i < NT) {
      int key = sec ? srcKeyOf(ei, E, i) : dstKeyOf(ei, E, i);
      atomicAdd(&h[key >> 8], 1);   // LDS atomic (on-CU, cheap)
    }
  }
  __syncthreads();
  hist[(size_t)(sec * 256 + tid) * nblk + blk] = h[tid];
}

// ---------- generic exclusive scan over M ints (3 kernels) ----------
__global__ __launch_bounds__(1024) void exscan1_kernel(int* __restrict__ a, int* __restrict__ bsum,
                                                       int M) {
  __shared__ int ws[16];
  int t = threadIdx.x, lane = t & 63, w = t >> 6;
  int i = blockIdx.x * 1024 + t;
  int v = (i < M) ? a[i] : 0;
  int x = v;
#pragma unroll
  for (int s = 1; s < 64; s <<= 1) {
    int tt = __shfl_up(x, s, 64);
    if (lane >= s) x += tt;
  }
  if (lane == 63) ws[w] = x;
  __syncthreads();
  int wo = 0;
  for (int k = 0; k < w; ++k) wo += ws[k];
  if (i < M) a[i] = wo + x - v;
  if (t == 1023) bsum[blockIdx.x] = wo + x;
}

__global__ __launch_bounds__(512) void exscan2_kernel(int* __restrict__ bsum, int nb) {
  __shared__ int buf[512];
  int t = threadIdx.x;
  int v = (t < nb) ? bsum[t] : 0;
  buf[t] = v;
  __syncthreads();
  for (int s = 1; s < 512; s <<= 1) {
    int x = (t >= s) ? buf[t - s] : 0;
    __syncthreads();
    buf[t] += x;
    __syncthreads();
  }
  if (t < nb) bsum[t] = buf[t] - v;
}

__global__ __launch_bounds__(1024) void exscan3_kernel(int* __restrict__ a,
                                                       const int* __restrict__ bsum, int M) {
  int i = blockIdx.x * 1024 + threadIdx.x;
  if (i < M) a[i] += bsum[blockIdx.x];
}

// ---------- sort pass 1 scatter: high-byte buckets (positions from scanned hist) ----------
__global__ __launch_bounds__(256) void scatter1_kernel(const int* __restrict__ ei, int E, int NT,
                                                       int nblk, const int* __restrict__ scanned,
                                                       int2* __restrict__ p1buf) {
  __shared__ int bins[256];
  int tid = threadIdx.x;
  int sec = (int)blockIdx.x >= nblk;
  int blk = blockIdx.x - sec * nblk;
  bins[tid] = scanned[(size_t)(sec * 256 + tid) * nblk + blk];
  __syncthreads();
  int base = blk * 1024;
#pragma unroll
  for (int j = 0; j < 4; ++j) {
    int i = base + j * 256 + tid;
    if (i < NT) {
      int k, p;
      if (sec == 0) { k = dstKeyOf(ei, E, i); p = srcKeyOf(ei, E, i); }
      else          { k = srcKeyOf(ei, E, i); p = dstKeyOf(ei, E, i); }
      int pos = atomicAdd(&bins[k >> 8], 1);   // LDS atomic
      p1buf[pos] = make_int2(k, p);
    }
  }
}

// ---------- sort pass 2: per-bucket low-byte sort in LDS ----------
// grid 512: [0,256) dst buckets -> keyD/srcD; [256,512) src buckets -> keyS/dstS
__global__ __launch_bounds__(1024) void sortlow_kernel(const int* __restrict__ scanned,
                                                       const int2* __restrict__ p1buf,
                                                       int nblk, int NT,
                                                       int* __restrict__ keyD, int* __restrict__ srcD,
                                                       int* __restrict__ keyS, int* __restrict__ dstS) {
  __shared__ int h[256];
  __shared__ int b2[256];
  int tid = threadIdx.x;
  int w = blockIdx.x;
  int sec = w >= 256;
  int d0 = w - sec * 256;
  int beg = scanned[(size_t)(sec * 256 + d0) * nblk];
  int end = (w == 511) ? 2 * NT : scanned[(size_t)(sec * 256 + d0 + 1) * nblk];
  if (tid < 256) h[tid] = 0;
  __syncthreads();
  for (int i = beg + tid; i < end; i += 1024) atomicAdd(&h[p1buf[i].x & 255], 1);
  __syncthreads();
  // exclusive scan of h -> absolute bases in b2
  if (tid < 256) b2[tid] = h[tid];
  __syncthreads();
  for (int s = 1; s < 256; s <<= 1) {
    int x = (tid >= s && tid < 256) ? b2[tid - s] : 0;
    __syncthreads();
    if (tid < 256) b2[tid] += x;
    __syncthreads();
  }
  if (tid < 256) b2[tid] = beg + b2[tid] - h[tid];
  __syncthreads();
  for (int i = beg + tid; i < end; i += 1024) {
    int2 it = p1buf[i];
    int pos = atomicAdd(&b2[it.x & 255], 1);   // LDS atomic; unstable = fine (grouping only)
    if (sec == 0) { keyD[pos] = it.x; srcD[pos] = it.y; }
    else          { keyS[pos - NT] = it.x; dstS[pos - NT] = it.y; }
  }
}

// ---------- segment offsets via binary search ----------
__global__ void bounds_kernel(const int* __restrict__ keyD, const int* __restrict__ keyS,
                              int* __restrict__ off, int* __restrict__ offS, int NT, int n) {
  int x = blockIdx.x * 256 + threadIdx.x;
  if (x == 0) { off[n] = NT; offS[n] = NT; }
  if (x >= 2 * n) return;
  int sec = x >= n;
  int d = x - sec * n;
  const int* key = sec ? keyS : keyD;
  int lo = 0, hi = NT;
  while (lo < hi) {
    int mid = (lo + hi) >> 1;
    if (key[mid] < d) lo = mid + 1; else hi = mid;
  }
  if (sec) offS[d] = lo; else off[d] = lo;
}

// ---------- layer-1 aggregation in EMBEDDING space ----------
// 4 groups x 16 lanes + 2-edge unroll = 8 gather chains in flight, cheap 40-shuffle epilogue
__global__ __launch_bounds__(128) void agg_emb_kernel(
    const int* __restrict__ off, const int* __restrict__ csr_src,
    const __bf16* __restrict__ embb, const float* __restrict__ as_,
    const float* __restrict__ ad_, __bf16* __restrict__ aggE) {
  int d = blockIdx.x * 2 + (threadIdx.x >> 6);
  int lane = threadIdx.x & 63;
  int g = lane >> 4, p = lane & 15;
  float4 adv = *(const float4*)(ad_ + (size_t)d * 4);
  float acc[4][4] = {};   // [head][chan]
  float wsum[4] = {};
  int beg = off[d], end = off[d + 1];
  for (int i0 = beg; i0 < end; i0 += 8) {
    int iA = i0 + g, iB = i0 + 4 + g;
    int idxA = (iA < end) ? iA : (end - 1);
    int idxB = (iB < end) ? iB : (end - 1);
    float vmA = (iA < end) ? 1.f : 0.f;
    float vmB = (iB < end) ? 1.f : 0.f;
    int sA = csr_src[idxA];
    int sB = csr_src[idxB];
    float4 aA = *(const float4*)(as_ + (size_t)sA * 4);
    float4 aB = *(const float4*)(as_ + (size_t)sB * 4);
    bf16x4 vA = *(const bf16x4*)(embb + (size_t)sA * 64 + p * 4);
    bf16x4 vB = *(const bf16x4*)(embb + (size_t)sB * 64 + p * 4);
    float lA0 = aA.x + adv.x; lA0 = lA0 >= 0.f ? lA0 : NEG_SLOPE * lA0;
    float lA1 = aA.y + adv.y; lA1 = lA1 >= 0.f ? lA1 : NEG_SLOPE * lA1;
    float lA2 = aA.z + adv.z; lA2 = lA2 >= 0.f ? lA2 : NEG_SLOPE * lA2;
    float lA3 = aA.w + adv.w; lA3 = lA3 >= 0.f ? lA3 : NEG_SLOPE * lA3;
    float lB0 = aB.x + adv.x; lB0 = lB0 >= 0.f ? lB0 : NEG_SLOPE * lB0;
    float lB1 = aB.y + adv.y; lB1 = lB1 >= 0.f ? lB1 : NEG_SLOPE * lB1;
    float lB2 = aB.z + adv.z; lB2 = lB2 >= 0.f ? lB2 : NEG_SLOPE * lB2;
    float lB3 = aB.w + adv.w; lB3 = lB3 >= 0.f ? lB3 : NEG_SLOPE * lB3;
    float wA0 = __expf(lA0) * vmA, wA1 = __expf(lA1) * vmA;
    float wA2 = __expf(lA2) * vmA, wA3 = __expf(lA3) * vmA;
    float wB0 = __expf(lB0) * vmB, wB1 = __expf(lB1) * vmB;
    float wB2 = __expf(lB2) * vmB, wB3 = __expf(lB3) * vmB;
    float fA0 = (float)vA[0], fA1 = (float)vA[1], fA2 = (float)vA[2], fA3 = (float)vA[3];
    float fB0 = (float)vB[0], fB1 = (float)vB[1], fB2 = (float)vB[2], fB3 = (float)vB[3];
    acc[0][0] += wA0 * fA0; acc[0][1] += wA0 * fA1; acc[0][2] += wA0 * fA2; acc[0][3] += wA0 * fA3;
    acc[1][0] += wA1 * fA0; acc[1][1] += wA1 * fA1; acc[1][2] += wA1 * fA2; acc[1][3] += wA1 * fA3;
    acc[2][0] += wA2 * fA0; acc[2][1] += wA2 * fA1; acc[2][2] += wA2 * fA2; acc[2][3] += wA2 * fA3;
    acc[3][0] += wA3 * fA0; acc[3][1] += wA3 * fA1; acc[3][2] += wA3 * fA2; acc[3][3] += wA3 * fA3;
    acc[0][0] += wB0 * fB0; acc[0][1] += wB0 * fB1; acc[0][2] += wB0 * fB2; acc[0][3] += wB0 * fB3;
    acc[1][0] += wB1 * fB0; acc[1][1] += wB1 * fB1; acc[1][2] += wB1 * fB2; acc[1][3] += wB1 * fB3;
    acc[2][0] += wB2 * fB0; acc[2][1] += wB2 * fB1; acc[2][2] += wB2 * fB2; acc[2][3] += wB2 * fB3;
    acc[3][0] += wB3 * fB0; acc[3][1] += wB3 * fB1; acc[3][2] += wB3 * fB2; acc[3][3] += wB3 * fB3;
    wsum[0] += wA0 + wB0; wsum[1] += wA1 + wB1; wsum[2] += wA2 + wB2; wsum[3] += wA3 + wB3;
  }
#pragma unroll
  for (int h = 0; h < 4; ++h) {
#pragma unroll
    for (int c = 0; c < 4; ++c) {
      acc[h][c] += __shfl_xor(acc[h][c], 16, 64);
      acc[h][c] += __shfl_xor(acc[h][c], 32, 64);
    }
    wsum[h] += __shfl_xor(wsum[h], 16, 64);
    wsum[h] += __shfl_xor(wsum[h], 32, 64);
  }
  if (g == 0) {
#pragma unroll
    for (int h = 0; h < 4; ++h) {
      float inv = 1.0f / wsum[h];
      bf16x4 o;
      o[0] = (__bf16)(acc[h][0] * inv); o[1] = (__bf16)(acc[h][1] * inv);
      o[2] = (__bf16)(acc[h][2] * inv); o[3] = (__bf16)(acc[h][3] * inv);
      *(bf16x4*)(aggE + (size_t)d * 256 + h * 64 + p * 4) = o;
    }
  }
}

// ---------- reconstruct x1 (per-head MFMA GEMM + bias + ELU) with fused alpha2 partials ----------
__global__ __launch_bounds__(256) void gemm1p_kernel(const __bf16* __restrict__ aggE,
                                                     const __bf16* __restrict__ W1T,
                                                     const float* __restrict__ b1,
                                                     const float* __restrict__ vs2,
                                                     const float* __restrict__ vd2,
                                                     __bf16* __restrict__ x1,
                                                     float* __restrict__ as2p,
                                                     float* __restrict__ ad2p, int M) {
  __shared__ __bf16 Asl[128 * 72];
  __shared__ __bf16 Bsl[128 * 72];
  int tid = threadIdx.x;
  int h = blockIdx.z;
  int m0 = blockIdx.x * 128;
  int wave = tid >> 6, lane = tid & 63;
  int wm = (wave >> 1) * 64, wn = (wave & 1) * 64;
  int l15 = lane & 15, kg = lane >> 4;
#pragma unroll
  for (int i = 0; i < 4; ++i) {
    int c = tid + i * 256;
    int row = c >> 3, off = (c & 7) * 8;
    bf16x8 va = {};
    int gr = m0 + row;
    if (gr < M) va = *(const bf16x8*)(aggE + (size_t)gr * 256 + h * 64 + off);
    *(bf16x8*)(&Asl[row * 72 + off]) = va;
    bf16x8 vb = *(const bf16x8*)(W1T + ((size_t)h * 128 + row) * 64 + off);
    *(bf16x8*)(&Bsl[row * 72 + off]) = vb;
  }
  __syncthreads();
  f32x4 acc[4][4] = {};
#pragma unroll
  for (int ks = 0; ks < 2; ++ks) {
    bf16x8 af[4], bfr[4];
#pragma unroll
    for (int f = 0; f < 4; ++f) {
      af[f]  = *(const bf16x8*)(&Asl[(wm + f * 16 + l15) * 72 + kg * 8 + ks * 32]);
      bfr[f] = *(const bf16x8*)(&Bsl[(wn + f * 16 + l15) * 72 + kg * 8 + ks * 32]);
    }
#pragma unroll
    for (int i = 0; i < 4; ++i)
#pragma unroll
      for (int j = 0; j < 4; ++j)
        acc[i][j] = __builtin_amdgcn_mfma_f32_16x16x32_bf16(af[i], bfr[j], acc[i][j], 0, 0, 0);
  }
  float bv[4], vsv[4], vdv[4];
#pragma unroll
  for (int j = 0; j < 4; ++j) {
    int col = h * 128 + wn + j * 16 + l15;
    bv[j] = b1[col]; vsv[j] = vs2[col]; vdv[j] = vd2[col];
  }
  int slab = h * 2 + (wn >> 6);
#pragma unroll
  for (int i = 0; i < 4; ++i)
#pragma unroll
    for (int r = 0; r < 4; ++r) {
      int lrow = wm + i * 16 + kg * 4 + r;
      int row = m0 + lrow;
      bool vrow = row < M;
      float ps = 0.f, pd = 0.f;
#pragma unroll
      for (int j = 0; j < 4; ++j) {
        float a = acc[i][j][r] + bv[j];
        a = a > 0.f ? a : __expf(a) - 1.f;   // ELU
        __bf16 xb = (__bf16)a;
        if (vrow) x1[(size_t)row * 512 + h * 128 + wn + j * 16 + l15] = xb;
        float af = (float)xb;
        ps += af * vsv[j];
        pd += af * vdv[j];
      }
      ps += __shfl_xor(ps, 1, 16); ps += __shfl_xor(ps, 2, 16);
      ps += __shfl_xor(ps, 4, 16); ps += __shfl_xor(ps, 8, 16);
      pd += __shfl_xor(pd, 1, 16); pd += __shfl_xor(pd, 2, 16);
      pd += __shfl_xor(pd, 4, 16); pd += __shfl_xor(pd, 8, 16);
      if (l15 == 0 && vrow) {
        as2p[(size_t)slab * M + row] = ps;
        ad2p[(size_t)slab * M + row] = pd;
      }
    }
}

// ---------- merge alpha2 partial slabs ----------
__global__ void merge_alpha2_kernel(const float* __restrict__ as2p, const float* __restrict__ ad2p,
                                    float* __restrict__ as2, float* __restrict__ ad2, int n) {
  int i = blockIdx.x * blockDim.x + threadIdx.x;
  if (i >= n) return;
  float s = 0.f, d = 0.f;
#pragma unroll
  for (int b = 0; b < 8; ++b) {
    s += as2p[(size_t)b * n + i];
    d += ad2p[(size_t)b * n + i];
  }
  as2[i] = s; ad2[i] = d;
}

// ---------- layer-2 denom: advw[d] = {ad2[d], invN / sum_e w_e} (CSR walk, no atomics) ----------
__global__ __launch_bounds__(256) void invw_kernel(
    const int* __restrict__ off, const int* __restrict__ csr_src,
    const float* __restrict__ as2, const float* __restrict__ ad2,
    float2* __restrict__ advw, float invN, int n) {
  int d = (blockIdx.x * 256 + threadIdx.x) >> 4;
  int p = threadIdx.x & 15;
  if (d >= n) return;
  float adv = ad2[d];
  int beg = off[d], end = off[d + 1];
  float wsum = 0.f;
  for (int i = beg + p; i < end; i += 16) {
    float l = as2[csr_src[i]] + adv;
    l = l >= 0.f ? l : NEG_SLOPE * l;
    wsum += __expf(l);
  }
  wsum += __shfl_xor(wsum, 1, 16); wsum += __shfl_xor(wsum, 2, 16);
  wsum += __shfl_xor(wsum, 4, 16); wsum += __shfl_xor(wsum, 8, 16);
  if (p == 0) advw[d] = make_float2(adv, invN / wsum);
}

// ---------- gamma via CSC walk (no atomics) ----------
__global__ __launch_bounds__(256) void gamma_csc_kernel(
    const int* __restrict__ offS, const int* __restrict__ csc_dst,
    const float* __restrict__ as2, const float2* __restrict__ advw,
    float* __restrict__ gamma, int n) {
  int s = (blockIdx.x * 256 + threadIdx.x) >> 4;
  int p = threadIdx.x & 15;
  if (s >= n) return;
  float as2s = as2[s];
  int beg = offS[s], end = offS[s + 1];
  float gsum = 0.f;
  for (int i = beg + p; i < end; i += 16) {
    float2 av = advw[csc_dst[i]];
    float l = as2s + av.x;
    l = l >= 0.f ? l : NEG_SLOPE * l;
    gsum += __expf(l) * av.y;
  }
  gsum += __shfl_xor(gsum, 1, 16); gsum += __shfl_xor(gsum, 2, 16);
  gsum += __shfl_xor(gsum, 4, 16); gsum += __shfl_xor(gsum, 8, 16);
  if (p == 0) gamma[s] = gsum;
}

// ---------- weighted column sum stage 1 ----------
__global__ __launch_bounds__(256) void colsum1_kernel(const __bf16* __restrict__ x1,
                                                      const float* __restrict__ gamma,
                                                      float* __restrict__ pcol, int n) {
  __shared__ float sc[512];
  int t = threadIdx.x;
  sc[t] = 0.f; sc[t + 256] = 0.f;
  __syncthreads();
  int lane = t & 63, w = t >> 6;
  float acc[8] = {};
  for (int r = blockIdx.x * 4 + w; r < n; r += gridDim.x * 4) {
    float g = gamma[r];
    bf16x8 v = *(const bf16x8*)(x1 + (size_t)r * 512 + lane * 8);
#pragma unroll
    for (int j = 0; j < 8; ++j) acc[j] += g * (float)v[j];
  }
#pragma unroll
  for (int j = 0; j < 8; ++j) atomicAdd(&sc[lane * 8 + j], acc[j]);
  __syncthreads();
  pcol[(size_t)blockIdx.x * 512 + t] = sc[t];
  pcol[(size_t)blockIdx.x * 512 + 256 + t] = sc[t + 256];
}

// stage 2: parallel block-sliced reduction
__global__ __launch_bounds__(256) void colsum2_kernel(const float* __restrict__ pcol,
                                                      float* __restrict__ colsum, int nb) {
  int c = threadIdx.x;
  int b0 = blockIdx.x * 16;
  float a0 = 0.f, a1 = 0.f;
#pragma unroll 4
  for (int b = b0; b < b0 + 16; ++b) {
    if (b < nb) {
      a0 += pcol[(size_t)b * 512 + c];
      a1 += pcol[(size_t)b * 512 + 256 + c];
    }
  }
  atomicAdd(&colsum[c], a0);
  atomicAdd(&colsum[c + 256], a1);
}

// ---------- final matvec: out[c] = colsum . W2[:,c] + b2[c] ----------
__global__ void final_kernel(const float* __restrict__ colsum, const float* __restrict__ W2,
                             const float* __restrict__ b2, float* __restrict__ out) {
  int c = threadIdx.x;  // 256
  int k0 = blockIdx.x * 64;  // 8 blocks x 64 k
  float acc = 0.f;
  for (int k = k0; k < k0 + 64; ++k) acc += colsum[k] * W2[(size_t)k * 256 + c];
  if (blockIdx.x == 0) acc += b2[c];
  atomicAdd(&out[c], acc);
}

__global__ void bcast_kernel(float* __restrict__ dout, int total) {
  int i = blockIdx.x * blockDim.x + threadIdx.x;
  if (i >= 256 && i < total) dout[i] = dout[i & 255];
}

// ---------- host ----------
extern "C" void kernel_launch(void* const* d_in, const int* in_sizes, int n_in,
                              void* d_out, int out_size, void* d_ws, size_t ws_size,
                              hipStream_t stream) {
  const int* ei = (const int*)d_in[0];
  const float* emb = (const float*)d_in[1];
  const float* W1 = (const float*)d_in[2];
  const float* as1w = (const float*)d_in[3];
  const float* ad1w = (const float*)d_in[4];
  const float* b1 = (const float*)d_in[5];
  const float* W2 = (const float*)d_in[6];
  const float* as2w = (const float*)d_in[7];
  const float* ad2w = (const float*)d_in[8];
  const float* b2 = (const float*)d_in[9];
  float* out = (float*)d_out;

  const int E = in_sizes[0] / 2;
  const int N = in_sizes[1] / 64;
  const int NT = E + N;
  const int CS1 = 1024;                 // colsum stage-1 blocks
  const int nblk = (NT + 1023) / 1024;  // sort blocks per section
  const int M = 2 * 256 * nblk;         // hist size
  const int scanBlocks = (M + 1023) / 1024;

  char* ws = (char*)d_ws;
  size_t o = 0;
  auto alloc = [&](size_t bytes) { size_t r = o; o += (bytes + 255) & ~(size_t)255; return r; };
  __bf16* embb  = (__bf16*)(ws + alloc((size_t)N * 64 * 2));
  __bf16* aggE  = (__bf16*)(ws + alloc((size_t)N * 256 * 2));
  __bf16* x1    = (__bf16*)(ws + alloc((size_t)N * 512 * 2));
  __bf16* W1T   = (__bf16*)(ws + alloc((size_t)512 * 64 * 2));
  float* as1    = (float*)(ws + alloc((size_t)N * 4 * 4));
  float* ad1    = (float*)(ws + alloc((size_t)N * 4 * 4));
  float* as2    = (float*)(ws + alloc((size_t)N * 4));
  float* ad2    = (float*)(ws + alloc((size_t)N * 4));
  float* as2p   = (float*)(ws + alloc((size_t)8 * N * 4));
  float* ad2p   = (float*)(ws + alloc((size_t)8 * N * 4));
  float* pcol   = (float*)(ws + alloc((size_t)CS1 * 512 * 4));
  float2* advw  = (float2*)(ws + alloc((size_t)N * 8));
  float* gamma  = (float*)(ws + alloc((size_t)N * 4));
  int* off      = (int*)(ws + alloc((size_t)(N + 1) * 4));
  int* offS     = (int*)(ws + alloc((size_t)(N + 1) * 4));
  int* keyD     = (int*)(ws + alloc((size_t)NT * 4));
  int* srcD     = (int*)(ws + alloc((size_t)NT * 4));   // csr_src (by dst)
  int* keyS     = (int*)(ws + alloc((size_t)NT * 4));
  int* dstS     = (int*)(ws + alloc((size_t)NT * 4));   // csc_dst (by src)
  int2* p1buf   = (int2*)(ws + alloc((size_t)2 * NT * 8));
  int* hist     = (int*)(ws + alloc((size_t)M * 4));
  int* bsum     = (int*)(ws + alloc(512 * 4));
  size_t zbeg = o;
  float* colsum = (float*)(ws + alloc(512 * 4));
  size_t zend = o;
  float* Vs1    = (float*)(ws + alloc(64 * 4 * 4));
  float* Vd1    = (float*)(ws + alloc(64 * 4 * 4));
  float* vs2    = (float*)(ws + alloc(512 * 4));
  float* vd2    = (float*)(ws + alloc(512 * 4));

  hipMemsetAsync(ws + zbeg, 0, zend - zbeg, stream);
  hipMemsetAsync(d_out, 0, (size_t)out_size * 4, stream);

  // prep (weights) + per-node alpha1 / bf16 emb
  prep_all_kernel<<<131, 256, 0, stream>>>(W1, as1w, ad1w, W2, as2w, ad2w,
                                           Vs1, Vd1, vs2, vd2, W1T);
  int nb = (N + 255) / 256;
  emb_prep_kernel<<<nb, 256, 0, stream>>>(emb, Vs1, Vd1, embb, as1, ad1, N);

  // atomic-free CSR (by dst) + CSC (by src) via MSD radix sort
  hist_kernel<<<2 * nblk, 256, 0, stream>>>(ei, E, NT, nblk, hist);
  exscan1_kernel<<<scanBlocks, 1024, 0, stream>>>(hist, bsum, M);
  exscan2_kernel<<<1, 512, 0, stream>>>(bsum, scanBlocks);
  exscan3_kernel<<<scanBlocks, 1024, 0, stream>>>(hist, bsum, M);
  scatter1_kernel<<<2 * nblk, 256, 0, stream>>>(ei, E, NT, nblk, hist, p1buf);
  sortlow_kernel<<<512, 1024, 0, stream>>>(hist, p1buf, nblk, NT, keyD, srcD, keyS, dstS);
  bounds_kernel<<<(2 * N + 255) / 256, 256, 0, stream>>>(keyD, keyS, off, offS, NT, N);

  // layer 1
  agg_emb_kernel<<<N / 2, 128, 0, stream>>>(off, srcD, embb, as1, ad1, aggE);
  dim3 g1((N + 127) / 128, 1, 4);
  gemm1p_kernel<<<g1, 256, 0, stream>>>(aggE, W1T, b1, vs2, vd2, x1, as2p, ad2p, N);
  merge_alpha2_kernel<<<nb, 256, 0, stream>>>(as2p, ad2p, as2, ad2, N);

  // layer 2 collapsed: invW pack -> atomic-free gamma (CSC walk) -> colsum -> matvec
  invw_kernel<<<(N * 16 + 255) / 256, 256, 0, stream>>>(off, srcD, as2, ad2, advw,
                                                        1.0f / (float)N, N);
  gamma_csc_kernel<<<(N * 16 + 255) / 256, 256, 0, stream>>>(offS, dstS, as2, advw, gamma, N);
  colsum1_kernel<<<CS1, 256, 0, stream>>>(x1, gamma, pcol, N);
  colsum2_kernel<<<CS1 / 16, 256, 0, stream>>>(pcol, colsum, CS1);
  final_kernel<<<8, 256, 0, stream>>>(colsum, W2, b2, out);

  if (out_size > 256) {
    bcast_kernel<<<(out_size + 255) / 256, 256, 0, stream>>>(out, out_size);
  }
}

// Round 13
// 197.111 us; speedup vs baseline: 1.7596x; 1.0361x over previous
//
#include <hip/hip_runtime.h>
#include <cstdint>
#include <cstddef>

#define NEG_SLOPE 0.2f

typedef __bf16 bf16x8 __attribute__((ext_vector_type(8)));
typedef __bf16 bf16x4 __attribute__((ext_vector_type(4)));
typedef float f32x4 __attribute__((ext_vector_type(4)));

// edge i in [0,NT): real edge for i<E, self-loop (i-E, i-E) otherwise
__device__ __forceinline__ int dstKeyOf(const int* ei, int E, int i) {
  return (i < E) ? ei[E + i] : (i - E);
}
__device__ __forceinline__ int srcKeyOf(const int* ei, int E, int i) {
  return (i < E) ? ei[i] : (i - E);
}

// ---------- merged independent prep: prep_v1 | prep_v2 | W1 transpose | radix hist ----------
// blocks: [0] v1, [1,2] v2, [3,130] transpose, [131, 131+2*nblk) hist
__global__ __launch_bounds__(256) void prep_front_kernel(
    const float* __restrict__ W1, const float* __restrict__ as1, const float* __restrict__ ad1,
    const float* __restrict__ W2, const float* __restrict__ as2, const float* __restrict__ ad2,
    const int* __restrict__ ei, int E, int NT, int nblk,
    float* __restrict__ Vs, float* __restrict__ Vd,
    float* __restrict__ vs2, float* __restrict__ vd2,
    __bf16* __restrict__ W1T, int* __restrict__ hist) {
  int bid = blockIdx.x, tid = threadIdx.x;
  if (bid == 0) {
    int k = tid >> 2, h = tid & 3;
    const float* w = W1 + k * 512 + h * 128;
    const float* a1 = as1 + h * 128;
    const float* a2 = ad1 + h * 128;
    float s = 0.f, d = 0.f;
    for (int c = 0; c < 128; ++c) { float wv = w[c]; s += wv * a1[c]; d += wv * a2[c]; }
    Vs[k * 4 + h] = s; Vd[k * 4 + h] = d;
  } else if (bid <= 2) {
    int k = (bid - 1) * 256 + tid;
    if (k < 512) {
      const float* w = W2 + k * 256;
      float s = 0.f, d = 0.f;
      for (int c = 0; c < 256; ++c) { float wv = w[c]; s += wv * as2[c]; d += wv * ad2[c]; }
      vs2[k] = s; vd2[k] = d;
    }
  } else if (bid <= 130) {
    int idx = (bid - 3) * 256 + tid;   // < 32768
    int n = idx >> 6, k = idx & 63;    // W1T[n*64+k] = W1[k*512+n]
    W1T[idx] = (__bf16)W1[(size_t)k * 512 + n];
  } else {
    __shared__ int h[256];
    h[tid] = 0;
    __syncthreads();
    int hblk = bid - 131;
    int sec = hblk >= nblk;
    int blk = hblk - sec * nblk;
    int base = blk * 1024;
#pragma unroll
    for (int j = 0; j < 4; ++j) {
      int i = base + j * 256 + tid;
      if (i < NT) {
        int key = sec ? srcKeyOf(ei, E, i) : dstKeyOf(ei, E, i);
        atomicAdd(&h[key >> 8], 1);   // LDS atomic (on-CU, cheap)
      }
    }
    __syncthreads();
    hist[(size_t)(sec * 256 + tid) * nblk + blk] = h[tid];
  }
}

// ---------- fused emb -> bf16 + alpha1 ----------
__global__ void emb_prep_kernel(const float* __restrict__ emb, const float* __restrict__ Vs,
                                const float* __restrict__ Vd, __bf16* __restrict__ embb,
                                float* __restrict__ as_, float* __restrict__ ad_, int n) {
  __shared__ float sVs[256];
  __shared__ float sVd[256];
  for (int i = threadIdx.x; i < 256; i += blockDim.x) { sVs[i] = Vs[i]; sVd[i] = Vd[i]; }
  __syncthreads();
  int node = blockIdx.x * blockDim.x + threadIdx.x;
  if (node >= n) return;
  const float* xr = emb + (size_t)node * 64;
  __bf16* br = embb + (size_t)node * 64;
  float accs[4] = {}, accd[4] = {};
  for (int k = 0; k < 64; k += 4) {
    float4 xv = *(const float4*)(xr + k);
    bf16x4 o;
    o[0] = (__bf16)xv.x; o[1] = (__bf16)xv.y; o[2] = (__bf16)xv.z; o[3] = (__bf16)xv.w;
    *(bf16x4*)(br + k) = o;
#pragma unroll
    for (int h = 0; h < 4; ++h) {
      accs[h] += xv.x * sVs[(k + 0) * 4 + h] + xv.y * sVs[(k + 1) * 4 + h] +
                 xv.z * sVs[(k + 2) * 4 + h] + xv.w * sVs[(k + 3) * 4 + h];
      accd[h] += xv.x * sVd[(k + 0) * 4 + h] + xv.y * sVd[(k + 1) * 4 + h] +
                 xv.z * sVd[(k + 2) * 4 + h] + xv.w * sVd[(k + 3) * 4 + h];
    }
  }
#pragma unroll
  for (int h = 0; h < 4; ++h) {
    as_[(size_t)node * 4 + h] = accs[h];
    ad_[(size_t)node * 4 + h] = accd[h];
  }
}

// ---------- exclusive scan over M ints (2 kernels; consumers fold bsum inline) ----------
__global__ __launch_bounds__(1024) void exscan1_kernel(int* __restrict__ a, int* __restrict__ bsum,
                                                       int M) {
  __shared__ int ws[16];
  int t = threadIdx.x, lane = t & 63, w = t >> 6;
  int i = blockIdx.x * 1024 + t;
  int v = (i < M) ? a[i] : 0;
  int x = v;
#pragma unroll
  for (int s = 1; s < 64; s <<= 1) {
    int tt = __shfl_up(x, s, 64);
    if (lane >= s) x += tt;
  }
  if (lane == 63) ws[w] = x;
  __syncthreads();
  int wo = 0;
  for (int k = 0; k < w; ++k) wo += ws[k];
  if (i < M) a[i] = wo + x - v;
  if (t == 1023) bsum[blockIdx.x] = wo + x;
}

__global__ __launch_bounds__(512) void exscan2_kernel(int* __restrict__ bsum, int nb) {
  __shared__ int buf[512];
  int t = threadIdx.x;
  int v = (t < nb) ? bsum[t] : 0;
  buf[t] = v;
  __syncthreads();
  for (int s = 1; s < 512; s <<= 1) {
    int x = (t >= s) ? buf[t - s] : 0;
    __syncthreads();
    buf[t] += x;
    __syncthreads();
  }
  if (t < nb) bsum[t] = buf[t] - v;
}

__device__ __forceinline__ int scannedAt(const int* hist, const int* bsum, size_t idx) {
  return hist[idx] + bsum[idx >> 10];
}

// ---------- sort pass 1 scatter: high-byte buckets ----------
__global__ __launch_bounds__(256) void scatter1_kernel(const int* __restrict__ ei, int E, int NT,
                                                       int nblk, const int* __restrict__ hist,
                                                       const int* __restrict__ bsum,
                                                       int2* __restrict__ p1buf) {
  __shared__ int bins[256];
  int tid = threadIdx.x;
  int sec = (int)blockIdx.x >= nblk;
  int blk = blockIdx.x - sec * nblk;
  bins[tid] = scannedAt(hist, bsum, (size_t)(sec * 256 + tid) * nblk + blk);
  __syncthreads();
  int base = blk * 1024;
#pragma unroll
  for (int j = 0; j < 4; ++j) {
    int i = base + j * 256 + tid;
    if (i < NT) {
      int k, p;
      if (sec == 0) { k = dstKeyOf(ei, E, i); p = srcKeyOf(ei, E, i); }
      else          { k = srcKeyOf(ei, E, i); p = dstKeyOf(ei, E, i); }
      int pos = atomicAdd(&bins[k >> 8], 1);   // LDS atomic
      p1buf[pos] = make_int2(k, p);
    }
  }
}

// ---------- sort pass 2: per-bucket low-byte sort in LDS ----------
__global__ __launch_bounds__(1024) void sortlow_kernel(const int* __restrict__ hist,
                                                       const int* __restrict__ bsum,
                                                       const int2* __restrict__ p1buf,
                                                       int nblk, int NT,
                                                       int* __restrict__ keyD, int* __restrict__ srcD,
                                                       int* __restrict__ keyS, int* __restrict__ dstS) {
  __shared__ int h[256];
  __shared__ int b2[256];
  int tid = threadIdx.x;
  int w = blockIdx.x;
  int sec = w >= 256;
  int d0 = w - sec * 256;
  int beg = scannedAt(hist, bsum, (size_t)(sec * 256 + d0) * nblk);
  int end = (w == 511) ? 2 * NT : scannedAt(hist, bsum, (size_t)(sec * 256 + d0 + 1) * nblk);
  if (tid < 256) h[tid] = 0;
  __syncthreads();
  for (int i = beg + tid; i < end; i += 1024) atomicAdd(&h[p1buf[i].x & 255], 1);
  __syncthreads();
  if (tid < 256) b2[tid] = h[tid];
  __syncthreads();
  for (int s = 1; s < 256; s <<= 1) {
    int x = (tid >= s && tid < 256) ? b2[tid - s] : 0;
    __syncthreads();
    if (tid < 256) b2[tid] += x;
    __syncthreads();
  }
  if (tid < 256) b2[tid] = beg + b2[tid] - h[tid];
  __syncthreads();
  for (int i = beg + tid; i < end; i += 1024) {
    int2 it = p1buf[i];
    int pos = atomicAdd(&b2[it.x & 255], 1);   // LDS atomic; unstable = fine
    if (sec == 0) { keyD[pos] = it.x; srcD[pos] = it.y; }
    else          { keyS[pos - NT] = it.x; dstS[pos - NT] = it.y; }
  }
}

// ---------- post-sort: layer-1 edge weights (dst-order) | segment bounds ----------
// blocks [0, ewBlocks): ew4[i] = exp(leaky(as1[srcD[i]]+ad1[keyD[i]])) per head
// blocks [ewBlocks, ...): binary-search off/offS
__global__ __launch_bounds__(256) void post_sort_kernel(
    const int* __restrict__ keyD, const int* __restrict__ srcD, const int* __restrict__ keyS,
    const float* __restrict__ as1, const float* __restrict__ ad1,
    float4* __restrict__ ew4, int* __restrict__ off, int* __restrict__ offS,
    int NT, int n, int ewBlocks) {
  if ((int)blockIdx.x < ewBlocks) {
    int i = blockIdx.x * 256 + threadIdx.x;
    if (i >= NT) return;
    int s = srcD[i], d = keyD[i];
    float4 a = *(const float4*)(as1 + (size_t)s * 4);
    float4 b = *(const float4*)(ad1 + (size_t)d * 4);
    float l0 = a.x + b.x; l0 = l0 >= 0.f ? l0 : NEG_SLOPE * l0;
    float l1 = a.y + b.y; l1 = l1 >= 0.f ? l1 : NEG_SLOPE * l1;
    float l2 = a.z + b.z; l2 = l2 >= 0.f ? l2 : NEG_SLOPE * l2;
    float l3 = a.w + b.w; l3 = l3 >= 0.f ? l3 : NEG_SLOPE * l3;
    ew4[i] = make_float4(__expf(l0), __expf(l1), __expf(l2), __expf(l3));
  } else {
    int x = (blockIdx.x - ewBlocks) * 256 + threadIdx.x;
    if (x == 0) { off[n] = NT; offS[n] = NT; }
    if (x >= 2 * n) return;
    int sec = x >= n;
    int d = x - sec * n;
    const int* key = sec ? keyS : keyD;
    int lo = 0, hi = NT;
    while (lo < hi) {
      int mid = (lo + hi) >> 1;
      if (key[mid] < d) lo = mid + 1; else hi = mid;
    }
    if (sec) offS[d] = lo; else off[d] = lo;
  }
}

// ---------- layer-1 aggregation in EMBEDDING space (weights precomputed) ----------
// 4 groups x 16 lanes + 2-edge unroll = 8 gather chains; FMA-only loop body
__global__ __launch_bounds__(128) void agg_emb_kernel(
    const int* __restrict__ off, const int* __restrict__ srcD,
    const float4* __restrict__ ew4, const __bf16* __restrict__ embb,
    __bf16* __restrict__ aggE) {
  int d = blockIdx.x * 2 + (threadIdx.x >> 6);
  int lane = threadIdx.x & 63;
  int g = lane >> 4, p = lane & 15;
  float acc[4][4] = {};   // [head][chan]
  float wsum[4] = {};
  int beg = off[d], end = off[d + 1];
  for (int i0 = beg; i0 < end; i0 += 8) {
    int iA = i0 + g, iB = i0 + 4 + g;
    int idxA = (iA < end) ? iA : (end - 1);
    int idxB = (iB < end) ? iB : (end - 1);
    float vmA = (iA < end) ? 1.f : 0.f;
    float vmB = (iB < end) ? 1.f : 0.f;
    int sA = srcD[idxA];
    int sB = srcD[idxB];
    float4 wAv = ew4[idxA];
    float4 wBv = ew4[idxB];
    bf16x4 vA = *(const bf16x4*)(embb + (size_t)sA * 64 + p * 4);
    bf16x4 vB = *(const bf16x4*)(embb + (size_t)sB * 64 + p * 4);
    float wA0 = wAv.x * vmA, wA1 = wAv.y * vmA, wA2 = wAv.z * vmA, wA3 = wAv.w * vmA;
    float wB0 = wBv.x * vmB, wB1 = wBv.y * vmB, wB2 = wBv.z * vmB, wB3 = wBv.w * vmB;
    float fA0 = (float)vA[0], fA1 = (float)vA[1], fA2 = (float)vA[2], fA3 = (float)vA[3];
    float fB0 = (float)vB[0], fB1 = (float)vB[1], fB2 = (float)vB[2], fB3 = (float)vB[3];
    acc[0][0] += wA0 * fA0; acc[0][1] += wA0 * fA1; acc[0][2] += wA0 * fA2; acc[0][3] += wA0 * fA3;
    acc[1][0] += wA1 * fA0; acc[1][1] += wA1 * fA1; acc[1][2] += wA1 * fA2; acc[1][3] += wA1 * fA3;
    acc[2][0] += wA2 * fA0; acc[2][1] += wA2 * fA1; acc[2][2] += wA2 * fA2; acc[2][3] += wA2 * fA3;
    acc[3][0] += wA3 * fA0; acc[3][1] += wA3 * fA1; acc[3][2] += wA3 * fA2; acc[3][3] += wA3 * fA3;
    acc[0][0] += wB0 * fB0; acc[0][1] += wB0 * fB1; acc[0][2] += wB0 * fB2; acc[0][3] += wB0 * fB3;
    acc[1][0] += wB1 * fB0; acc[1][1] += wB1 * fB1; acc[1][2] += wB1 * fB2; acc[1][3] += wB1 * fB3;
    acc[2][0] += wB2 * fB0; acc[2][1] += wB2 * fB1; acc[2][2] += wB2 * fB2; acc[2][3] += wB2 * fB3;
    acc[3][0] += wB3 * fB0; acc[3][1] += wB3 * fB1; acc[3][2] += wB3 * fB2; acc[3][3] += wB3 * fB3;
    wsum[0] += wA0 + wB0; wsum[1] += wA1 + wB1; wsum[2] += wA2 + wB2; wsum[3] += wA3 + wB3;
  }
#pragma unroll
  for (int h = 0; h < 4; ++h) {
#pragma unroll
    for (int c = 0; c < 4; ++c) {
      acc[h][c] += __shfl_xor(acc[h][c], 16, 64);
      acc[h][c] += __shfl_xor(acc[h][c], 32, 64);
    }
    wsum[h] += __shfl_xor(wsum[h], 16, 64);
    wsum[h] += __shfl_xor(wsum[h], 32, 64);
  }
  if (g == 0) {
#pragma unroll
    for (int h = 0; h < 4; ++h) {
      float inv = 1.0f / wsum[h];
      bf16x4 o;
      o[0] = (__bf16)(acc[h][0] * inv); o[1] = (__bf16)(acc[h][1] * inv);
      o[2] = (__bf16)(acc[h][2] * inv); o[3] = (__bf16)(acc[h][3] * inv);
      *(bf16x4*)(aggE + (size_t)d * 256 + h * 64 + p * 4) = o;
    }
  }
}

// ---------- reconstruct x1 (per-head MFMA GEMM + bias + ELU) with fused alpha2 partials ----------
__global__ __launch_bounds__(256) void gemm1p_kernel(const __bf16* __restrict__ aggE,
                                                     const __bf16* __restrict__ W1T,
                                                     const float* __restrict__ b1,
                                                     const float* __restrict__ vs2,
                                                     const float* __restrict__ vd2,
                                                     __bf16* __restrict__ x1,
                                                     float* __restrict__ as2p,
                                                     float* __restrict__ ad2p, int M) {
  __shared__ __bf16 Asl[128 * 72];
  __shared__ __bf16 Bsl[128 * 72];
  int tid = threadIdx.x;
  int h = blockIdx.z;
  int m0 = blockIdx.x * 128;
  int wave = tid >> 6, lane = tid & 63;
  int wm = (wave >> 1) * 64, wn = (wave & 1) * 64;
  int l15 = lane & 15, kg = lane >> 4;
#pragma unroll
  for (int i = 0; i < 4; ++i) {
    int c = tid + i * 256;
    int row = c >> 3, off = (c & 7) * 8;
    bf16x8 va = {};
    int gr = m0 + row;
    if (gr < M) va = *(const bf16x8*)(aggE + (size_t)gr * 256 + h * 64 + off);
    *(bf16x8*)(&Asl[row * 72 + off]) = va;
    bf16x8 vb = *(const bf16x8*)(W1T + ((size_t)h * 128 + row) * 64 + off);
    *(bf16x8*)(&Bsl[row * 72 + off]) = vb;
  }
  __syncthreads();
  f32x4 acc[4][4] = {};
#pragma unroll
  for (int ks = 0; ks < 2; ++ks) {
    bf16x8 af[4], bfr[4];
#pragma unroll
    for (int f = 0; f < 4; ++f) {
      af[f]  = *(const bf16x8*)(&Asl[(wm + f * 16 + l15) * 72 + kg * 8 + ks * 32]);
      bfr[f] = *(const bf16x8*)(&Bsl[(wn + f * 16 + l15) * 72 + kg * 8 + ks * 32]);
    }
#pragma unroll
    for (int i = 0; i < 4; ++i)
#pragma unroll
      for (int j = 0; j < 4; ++j)
        acc[i][j] = __builtin_amdgcn_mfma_f32_16x16x32_bf16(af[i], bfr[j], acc[i][j], 0, 0, 0);
  }
  float bv[4], vsv[4], vdv[4];
#pragma unroll
  for (int j = 0; j < 4; ++j) {
    int col = h * 128 + wn + j * 16 + l15;
    bv[j] = b1[col]; vsv[j] = vs2[col]; vdv[j] = vd2[col];
  }
  int slab = h * 2 + (wn >> 6);
#pragma unroll
  for (int i = 0; i < 4; ++i)
#pragma unroll
    for (int r = 0; r < 4; ++r) {
      int lrow = wm + i * 16 + kg * 4 + r;
      int row = m0 + lrow;
      bool vrow = row < M;
      float ps = 0.f, pd = 0.f;
#pragma unroll
      for (int j = 0; j < 4; ++j) {
        float a = acc[i][j][r] + bv[j];
        a = a > 0.f ? a : __expf(a) - 1.f;   // ELU
        __bf16 xb = (__bf16)a;
        if (vrow) x1[(size_t)row * 512 + h * 128 + wn + j * 16 + l15] = xb;
        float af = (float)xb;
        ps += af * vsv[j];
        pd += af * vdv[j];
      }
      ps += __shfl_xor(ps, 1, 16); ps += __shfl_xor(ps, 2, 16);
      ps += __shfl_xor(ps, 4, 16); ps += __shfl_xor(ps, 8, 16);
      pd += __shfl_xor(pd, 1, 16); pd += __shfl_xor(pd, 2, 16);
      pd += __shfl_xor(pd, 4, 16); pd += __shfl_xor(pd, 8, 16);
      if (l15 == 0 && vrow) {
        as2p[(size_t)slab * M + row] = ps;
        ad2p[(size_t)slab * M + row] = pd;
      }
    }
}

// ---------- merge alpha2 partial slabs ----------
__global__ void merge_alpha2_kernel(const float* __restrict__ as2p, const float* __restrict__ ad2p,
                                    float* __restrict__ as2, float* __restrict__ ad2, int n) {
  int i = blockIdx.x * blockDim.x + threadIdx.x;
  if (i >= n) return;
  float s = 0.f, d = 0.f;
#pragma unroll
  for (int b = 0; b < 8; ++b) {
    s += as2p[(size_t)b * n + i];
    d += ad2p[(size_t)b * n + i];
  }
  as2[i] = s; ad2[i] = d;
}

// ---------- layer-2 denom: advw[d] = {ad2[d], invN / sum_e w_e} (CSR walk, no atomics) ----------
__global__ __launch_bounds__(256) void invw_kernel(
    const int* __restrict__ off, const int* __restrict__ csr_src,
    const float* __restrict__ as2, const float* __restrict__ ad2,
    float2* __restrict__ advw, float invN, int n) {
  int d = (blockIdx.x * 256 + threadIdx.x) >> 4;
  int p = threadIdx.x & 15;
  if (d >= n) return;
  float adv = ad2[d];
  int beg = off[d], end = off[d + 1];
  float wsum = 0.f;
  for (int i = beg + p; i < end; i += 16) {
    float l = as2[csr_src[i]] + adv;
    l = l >= 0.f ? l : NEG_SLOPE * l;
    wsum += __expf(l);
  }
  wsum += __shfl_xor(wsum, 1, 16); wsum += __shfl_xor(wsum, 2, 16);
  wsum += __shfl_xor(wsum, 4, 16); wsum += __shfl_xor(wsum, 8, 16);
  if (p == 0) advw[d] = make_float2(adv, invN / wsum);
}

// ---------- gamma via CSC walk (no atomics) ----------
__global__ __launch_bounds__(256) void gamma_csc_kernel(
    const int* __restrict__ offS, const int* __restrict__ csc_dst,
    const float* __restrict__ as2, const float2* __restrict__ advw,
    float* __restrict__ gamma, int n) {
  int s = (blockIdx.x * 256 + threadIdx.x) >> 4;
  int p = threadIdx.x & 15;
  if (s >= n) return;
  float as2s = as2[s];
  int beg = offS[s], end = offS[s + 1];
  float gsum = 0.f;
  for (int i = beg + p; i < end; i += 16) {
    float2 av = advw[csc_dst[i]];
    float l = as2s + av.x;
    l = l >= 0.f ? l : NEG_SLOPE * l;
    gsum += __expf(l) * av.y;
  }
  gsum += __shfl_xor(gsum, 1, 16); gsum += __shfl_xor(gsum, 2, 16);
  gsum += __shfl_xor(gsum, 4, 16); gsum += __shfl_xor(gsum, 8, 16);
  if (p == 0) gamma[s] = gsum;
}

// ---------- weighted column sum stage 1 ----------
__global__ __launch_bounds__(256) void colsum1_kernel(const __bf16* __restrict__ x1,
                                                      const float* __restrict__ gamma,
                                                      float* __restrict__ pcol, int n) {
  __shared__ float sc[512];
  int t = threadIdx.x;
  sc[t] = 0.f; sc[t + 256] = 0.f;
  __syncthreads();
  int lane = t & 63, w = t >> 6;
  float acc[8] = {};
  for (int r = blockIdx.x * 4 + w; r < n; r += gridDim.x * 4) {
    float g = gamma[r];
    bf16x8 v = *(const bf16x8*)(x1 + (size_t)r * 512 + lane * 8);
#pragma unroll
    for (int j = 0; j < 8; ++j) acc[j] += g * (float)v[j];
  }
#pragma unroll
  for (int j = 0; j < 8; ++j) atomicAdd(&sc[lane * 8 + j], acc[j]);
  __syncthreads();
  pcol[(size_t)blockIdx.x * 512 + t] = sc[t];
  pcol[(size_t)blockIdx.x * 512 + 256 + t] = sc[t + 256];
}

// stage 2: parallel block-sliced reduction
__global__ __launch_bounds__(256) void colsum2_kernel(const float* __restrict__ pcol,
                                                      float* __restrict__ colsum, int nb) {
  int c = threadIdx.x;
  int b0 = blockIdx.x * 16;
  float a0 = 0.f, a1 = 0.f;
#pragma unroll 4
  for (int b = b0; b < b0 + 16; ++b) {
    if (b < nb) {
      a0 += pcol[(size_t)b * 512 + c];
      a1 += pcol[(size_t)b * 512 + 256 + c];
    }
  }
  atomicAdd(&colsum[c], a0);
  atomicAdd(&colsum[c + 256], a1);
}

// ---------- final matvec: out[c] = colsum . W2[:,c] + b2[c] ----------
__global__ void final_kernel(const float* __restrict__ colsum, const float* __restrict__ W2,
                             const float* __restrict__ b2, float* __restrict__ out) {
  int c = threadIdx.x;  // 256
  int k0 = blockIdx.x * 64;  // 8 blocks x 64 k
  float acc = 0.f;
  for (int k = k0; k < k0 + 64; ++k) acc += colsum[k] * W2[(size_t)k * 256 + c];
  if (blockIdx.x == 0) acc += b2[c];
  atomicAdd(&out[c], acc);
}

__global__ void bcast_kernel(float* __restrict__ dout, int total) {
  int i = blockIdx.x * blockDim.x + threadIdx.x;
  if (i >= 256 && i < total) dout[i] = dout[i & 255];
}

// ---------- host ----------
extern "C" void kernel_launch(void* const* d_in, const int* in_sizes, int n_in,
                              void* d_out, int out_size, void* d_ws, size_t ws_size,
                              hipStream_t stream) {
  const int* ei = (const int*)d_in[0];
  const float* emb = (const float*)d_in[1];
  const float* W1 = (const float*)d_in[2];
  const float* as1w = (const float*)d_in[3];
  const float* ad1w = (const float*)d_in[4];
  const float* b1 = (const float*)d_in[5];
  const float* W2 = (const float*)d_in[6];
  const float* as2w = (const float*)d_in[7];
  const float* ad2w = (const float*)d_in[8];
  const float* b2 = (const float*)d_in[9];
  float* out = (float*)d_out;

  const int E = in_sizes[0] / 2;
  const int N = in_sizes[1] / 64;
  const int NT = E + N;
  const int CS1 = 1024;                 // colsum stage-1 blocks
  const int nblk = (NT + 1023) / 1024;  // sort blocks per section
  const int M = 2 * 256 * nblk;         // hist size
  const int scanBlocks = (M + 1023) / 1024;

  char* ws = (char*)d_ws;
  size_t o = 0;
  auto alloc = [&](size_t bytes) { size_t r = o; o += (bytes + 255) & ~(size_t)255; return r; };
  __bf16* embb  = (__bf16*)(ws + alloc((size_t)N * 64 * 2));
  __bf16* aggE  = (__bf16*)(ws + alloc((size_t)N * 256 * 2));
  __bf16* x1    = (__bf16*)(ws + alloc((size_t)N * 512 * 2));
  __bf16* W1T   = (__bf16*)(ws + alloc((size_t)512 * 64 * 2));
  float* as1    = (float*)(ws + alloc((size_t)N * 4 * 4));
  float* ad1    = (float*)(ws + alloc((size_t)N * 4 * 4));
  float* as2    = (float*)(ws + alloc((size_t)N * 4));
  float* ad2    = (float*)(ws + alloc((size_t)N * 4));
  float* as2p   = (float*)(ws + alloc((size_t)8 * N * 4));
  float* ad2p   = (float*)(ws + alloc((size_t)8 * N * 4));
  float* pcol   = (float*)(ws + alloc((size_t)CS1 * 512 * 4));
  float2* advw  = (float2*)(ws + alloc((size_t)N * 8));
  float* gamma  = (float*)(ws + alloc((size_t)N * 4));
  int* off      = (int*)(ws + alloc((size_t)(N + 1) * 4));
  int* offS     = (int*)(ws + alloc((size_t)(N + 1) * 4));
  int* keyD     = (int*)(ws + alloc((size_t)NT * 4));
  int* srcD     = (int*)(ws + alloc((size_t)NT * 4));   // csr_src (by dst)
  int* keyS     = (int*)(ws + alloc((size_t)NT * 4));
  int* dstS     = (int*)(ws + alloc((size_t)NT * 4));   // csc_dst (by src)
  int2* p1buf   = (int2*)(ws + alloc((size_t)2 * NT * 8));
  int* hist     = (int*)(ws + alloc((size_t)M * 4));
  int* bsum     = (int*)(ws + alloc(512 * 4));
  float4* ew4   = (float4*)(ws + alloc((size_t)NT * 16));
  size_t zbeg = o;
  float* colsum = (float*)(ws + alloc(512 * 4));
  size_t zend = o;
  float* Vs1    = (float*)(ws + alloc(64 * 4 * 4));
  float* Vd1    = (float*)(ws + alloc(64 * 4 * 4));
  float* vs2    = (float*)(ws + alloc(512 * 4));
  float* vd2    = (float*)(ws + alloc(512 * 4));

  hipMemsetAsync(ws + zbeg, 0, zend - zbeg, stream);
  hipMemsetAsync(d_out, 0, (size_t)out_size * 4, stream);

  // merged prep (weights) + radix histogram
  prep_front_kernel<<<131 + 2 * nblk, 256, 0, stream>>>(W1, as1w, ad1w, W2, as2w, ad2w,
                                                        ei, E, NT, nblk,
                                                        Vs1, Vd1, vs2, vd2, W1T, hist);
  int nb = (N + 255) / 256;
  emb_prep_kernel<<<nb, 256, 0, stream>>>(emb, Vs1, Vd1, embb, as1, ad1, N);

  // atomic-free CSR (by dst) + CSC (by src) via MSD radix sort
  exscan1_kernel<<<scanBlocks, 1024, 0, stream>>>(hist, bsum, M);
  exscan2_kernel<<<1, 512, 0, stream>>>(bsum, scanBlocks);
  scatter1_kernel<<<2 * nblk, 256, 0, stream>>>(ei, E, NT, nblk, hist, bsum, p1buf);
  sortlow_kernel<<<512, 1024, 0, stream>>>(hist, bsum, p1buf, nblk, NT, keyD, srcD, keyS, dstS);

  // edge weights (layer 1) + segment bounds, one dispatch
  int ewBlocks = (NT + 255) / 256;
  int bBlocks = (2 * N + 255) / 256;
  post_sort_kernel<<<ewBlocks + bBlocks, 256, 0, stream>>>(keyD, srcD, keyS, as1, ad1,
                                                           ew4, off, offS, NT, N, ewBlocks);

  // layer 1
  agg_emb_kernel<<<N / 2, 128, 0, stream>>>(off, srcD, ew4, embb, aggE);
  dim3 g1((N + 127) / 128, 1, 4);
  gemm1p_kernel<<<g1, 256, 0, stream>>>(aggE, W1T, b1, vs2, vd2, x1, as2p, ad2p, N);
  merge_alpha2_kernel<<<nb, 256, 0, stream>>>(as2p, ad2p, as2, ad2, N);

  // layer 2 collapsed: invW pack -> atomic-free gamma (CSC walk) -> colsum -> matvec
  invw_kernel<<<(N * 16 + 255) / 256, 256, 0, stream>>>(off, srcD, as2, ad2, advw,
                                                        1.0f / (float)N, N);
  gamma_csc_kernel<<<(N * 16 + 255) / 256, 256, 0, stream>>>(offS, dstS, as2, advw, gamma, N);
  colsum1_kernel<<<CS1, 256, 0, stream>>>(x1, gamma, pcol, N);
  colsum2_kernel<<<CS1 / 16, 256, 0, stream>>>(pcol, colsum, CS1);
  final_kernel<<<8, 256, 0, stream>>>(colsum, W2, b2, out);

  if (out_size > 256) {
    bcast_kernel<<<(out_size + 255) / 256, 256, 0, stream>>>(out, out_size);
  }
}